// Round 2
// baseline (556.362 us; speedup 1.0000x reference)
//
#include <hip/hip_runtime.h>
#include <math.h>

typedef __attribute__((ext_vector_type(8))) short s16x8;   // 8 bf16 (4 VGPRs)
typedef __attribute__((ext_vector_type(4))) float f32x4;   // MFMA accumulator
typedef __attribute__((ext_vector_type(4))) int   i32x4;

__device__ __forceinline__ short f2bf(float x){
  unsigned u = __float_as_uint(x);
  u += 0x7fff + ((u >> 16) & 1);        // round-to-nearest-even
  return (short)(u >> 16);
}
__device__ __forceinline__ float bf2f(short s){
  return __uint_as_float(((unsigned)(unsigned short)s) << 16);
}

// ---------------- fp32 -> bf16 convert (n % 4 == 0) ----------------
__global__ void k_cvt(const float* __restrict__ in, short* __restrict__ outb, int n4){
  int i = blockIdx.x*blockDim.x + threadIdx.x;
  if (i >= n4) return;
  float4 v = ((const float4*)in)[i];
  short4 u; u.x = f2bf(v.x); u.y = f2bf(v.y); u.z = f2bf(v.z); u.w = f2bf(v.w);
  ((short4*)outb)[i] = u;
}

// ---------------- weight transpose+convert: Wt[n][k] (bf16) from W[k][n] (fp32) ----------------
__global__ void k_wt(const float* W, short* Wt, int K){
  int idx = blockIdx.x*blockDim.x + threadIdx.x;
  if (idx >= 256*K) return;
  int n = idx / K, k = idx - n*K;
  Wt[idx] = f2bf(W[(size_t)k*256 + n]);
}

// c[h] = sum_f Wtp[h*F+f]*a_tp[h*F+f]
__global__ void k_cvec(const float* Wtp, const float* a_tp, float* c, int NH){
  __shared__ float buf[256];
  int t = threadIdx.x;
  buf[t] = Wtp[t] * a_tp[t];
  __syncthreads();
  int F = 256 / NH;
  if (t < NH){
    float s = 0.f;
    for (int f = 0; f < F; f++) s += buf[t*F + f];
    c[t] = s;
  }
}

// ---------------- CSR build (sort edges by target) ----------------
__global__ void k_zero(int* p, int n){
  int i = blockIdx.x*blockDim.x + threadIdx.x;
  if (i < n) p[i] = 0;
}
__global__ void k_hist(const int* tgt, int* counts, int E){
  int i = blockIdx.x*blockDim.x + threadIdx.x;
  if (i < E) atomicAdd(&counts[tgt[i]], 1);
}
__global__ void k_scan1(const int* counts, int* row_excl, int* partials, int N){
  __shared__ int buf[1024];
  int t = threadIdx.x; int i = blockIdx.x*1024 + t;
  int v = (i < N) ? counts[i] : 0;
  buf[t] = v; __syncthreads();
  for (int o = 1; o < 1024; o <<= 1){
    int x = (t >= o) ? buf[t-o] : 0;
    __syncthreads();
    buf[t] += x;
    __syncthreads();
  }
  if (i < N) row_excl[i] = buf[t] - v;
  if (t == 1023) partials[blockIdx.x] = buf[1023];
}
__global__ void k_scan2(int* partials, int NB){
  if (threadIdx.x == 0 && blockIdx.x == 0){
    int s = 0;
    for (int b = 0; b < NB; b++){ int v = partials[b]; partials[b] = s; s += v; }
  }
}
__global__ void k_scan3(int* row_start, const int* partials, int* cursor, int N, int E){
  int i = blockIdx.x*blockDim.x + threadIdx.x;
  if (i < N){
    int v = row_start[i] + partials[i >> 10];
    row_start[i] = v; cursor[i] = v;
  }
  if (i == 0) row_start[N] = E;
}
// pack (src, transition_prob) as int2 for one 8B load per edge in attention
__global__ void k_scatter(const int* src, const int* tgt, const float* eprob,
                          int* cursor, int2* es, int E){
  int i = blockIdx.x*blockDim.x + threadIdx.x;
  if (i >= E) return;
  int tg = tgt[i];
  int p = atomicAdd(&cursor[tg], 1);
  int2 v; v.x = src[i]; v.y = __float_as_int(eprob[i]);
  es[p] = v;
}

// ---------------- LDS-staged MFMA GEMM ----------------
// y=0: proj -> bf16 C1b + fused s_src/s_tgt (NH=16, from fp32 accs; skip if asrc null).
// y=1: skip -> bf16 C2b.
template<int KC>   // K/32 chunks: 4 (K=128) or 8 (K=256)
__global__ __launch_bounds__(256)
void k_gemm_lds(const short* __restrict__ Ab,
                const short* __restrict__ B1t, const short* __restrict__ B2t,
                short* __restrict__ C1b, short* __restrict__ C2b,
                const float* __restrict__ asrc, const float* __restrict__ atgt,
                float* __restrict__ s_src, float* __restrict__ s_tgt, int M){
  const int K = KC*32;
  __shared__ short lA[64*32];     // 4 KB
  __shared__ short lB[256*32];    // 16 KB
  const int tid  = threadIdx.x;
  const int lane = tid & 63;
  const int wave = tid >> 6;
  const int m16  = lane & 15;
  const int q    = lane >> 4;
  const int swz  = (m16 >> 1) & 3;
  const int r0   = blockIdx.x * 64;
  const bool first = (blockIdx.y == 0);
  const short* __restrict__ Bt = first ? B1t : B2t;
  short* __restrict__ Cb = first ? C1b : C2b;

  int arow = r0 + (tid >> 2); if (arow >= M) arow = M - 1;
  const int akq = (tid & 3) ^ ((tid >> 3) & 3);
  int bn[4], bkq[4];
  #pragma unroll
  for (int j = 0; j < 4; j++){
    int sj = j*256 + tid;
    bn[j]  = sj >> 2;
    bkq[j] = (sj & 3) ^ ((sj >> 3) & 3);
  }

  f32x4 acc[4][4];
  #pragma unroll
  for (int mi = 0; mi < 4; mi++)
    #pragma unroll
    for (int ni = 0; ni < 4; ni++) acc[mi][ni] = {0.f,0.f,0.f,0.f};

  s16x8 ra = *(const s16x8*)(Ab + (size_t)arow*K + akq*8);
  s16x8 rb[4];
  #pragma unroll
  for (int j = 0; j < 4; j++)
    rb[j] = *(const s16x8*)(Bt + (size_t)bn[j]*K + bkq[j]*8);

  for (int c = 0; c < KC; c++){
    __syncthreads();
    *(s16x8*)(lA + tid*8) = ra;
    #pragma unroll
    for (int j = 0; j < 4; j++)
      *(s16x8*)(lB + (j*256 + tid)*8) = rb[j];
    __syncthreads();

    if (c + 1 < KC){
      int k0 = (c+1)*32;
      ra = *(const s16x8*)(Ab + (size_t)arow*K + k0 + akq*8);
      #pragma unroll
      for (int j = 0; j < 4; j++)
        rb[j] = *(const s16x8*)(Bt + (size_t)bn[j]*K + k0 + bkq[j]*8);
    }

    s16x8 Af[4], Bf[4];
    #pragma unroll
    for (int mi = 0; mi < 4; mi++){
      int slot = (mi*16 + m16)*4 + (q ^ swz);
      Af[mi] = *(const s16x8*)(lA + slot*8);
    }
    #pragma unroll
    for (int ni = 0; ni < 4; ni++){
      int n = wave*64 + ni*16 + m16;
      int slot = n*4 + (q ^ swz);
      Bf[ni] = *(const s16x8*)(lB + slot*8);
    }
    #pragma unroll
    for (int mi = 0; mi < 4; mi++)
      #pragma unroll
      for (int ni = 0; ni < 4; ni++)
        acc[mi][ni] = __builtin_amdgcn_mfma_f32_16x16x32_bf16(Bf[ni], Af[mi], acc[mi][ni], 0, 0, 0);
  }

  #pragma unroll
  for (int mi = 0; mi < 4; mi++){
    int row = r0 + mi*16 + m16;
    bool ok = (row < M);
    #pragma unroll
    for (int ni = 0; ni < 4; ni++){
      if (ok){
        size_t o = (size_t)row*256 + wave*64 + ni*16 + q*4;
        short4 u; u.x = f2bf(acc[mi][ni][0]); u.y = f2bf(acc[mi][ni][1]);
        u.z = f2bf(acc[mi][ni][2]); u.w = f2bf(acc[mi][ni][3]);
        *(short4*)(Cb + o) = u;
      }
      if (first && asrc){
        // fused svec: head hh = wave*4+ni; lane holds features q*4..q*4+3 of row
        int hh = wave*4 + ni;
        const float* as = asrc + hh*16 + q*4;
        const float* at = atgt + hh*16 + q*4;
        float pss = acc[mi][ni][0]*as[0] + acc[mi][ni][1]*as[1]
                  + acc[mi][ni][2]*as[2] + acc[mi][ni][3]*as[3];
        float pst = acc[mi][ni][0]*at[0] + acc[mi][ni][1]*at[1]
                  + acc[mi][ni][2]*at[2] + acc[mi][ni][3]*at[3];
        pss += __shfl_xor(pss, 16); pss += __shfl_xor(pss, 32);
        pst += __shfl_xor(pst, 16); pst += __shfl_xor(pst, 32);
        if (ok && q == 0){
          s_src[row*16 + hh] = pss;
          s_tgt[row*16 + hh] = pst;
        }
      }
    }
  }
}

// ---------------- NH=1 score projections from bf16 proj (wave per node) ----------------
__global__ void k_svec1(const short* __restrict__ Pb,
                        const float* __restrict__ a_src, const float* __restrict__ a_tgt,
                        float* __restrict__ s_src, float* __restrict__ s_tgt, int N){
  int lane = threadIdx.x & 63;
  int node = blockIdx.x*(blockDim.x >> 6) + (threadIdx.x >> 6);
  if (node >= N) return;
  short4 p = ((const short4*)(Pb + (size_t)node*256))[lane];
  const float* as = a_src + lane*4;
  const float* at = a_tgt + lane*4;
  float f0 = bf2f(p.x), f1 = bf2f(p.y), f2 = bf2f(p.z), f3 = bf2f(p.w);
  float ss = f0*as[0] + f1*as[1] + f2*as[2] + f3*as[3];
  float st = f0*at[0] + f1*at[1] + f2*at[2] + f3*at[3];
  for (int o = 32; o > 0; o >>= 1){ ss += __shfl_xor(ss, o); st += __shfl_xor(st, o); }
  if (lane == 0){ s_src[node] = ss; s_tgt[node] = st; }
}

// 16 proj-row gathers issued back-to-back, then consumed. wq/sq are 4x f32x4 / i32x4.
#define AGG16(W0_,W1_,W2_,W3_,S0_,S1_,S2_,S3_)                                          \
  {                                                                                      \
    const short4* __restrict__ pp = (const short4*)projb + lane;                         \
    short4 p0  = pp[(size_t)S0_.x*64]; short4 p1  = pp[(size_t)S0_.y*64];                \
    short4 p2  = pp[(size_t)S0_.z*64]; short4 p3  = pp[(size_t)S0_.w*64];                \
    short4 p4  = pp[(size_t)S1_.x*64]; short4 p5  = pp[(size_t)S1_.y*64];                \
    short4 p6  = pp[(size_t)S1_.z*64]; short4 p7  = pp[(size_t)S1_.w*64];                \
    short4 p8  = pp[(size_t)S2_.x*64]; short4 p9  = pp[(size_t)S2_.y*64];                \
    short4 p10 = pp[(size_t)S2_.z*64]; short4 p11 = pp[(size_t)S2_.w*64];                \
    short4 p12 = pp[(size_t)S3_.x*64]; short4 p13 = pp[(size_t)S3_.y*64];                \
    short4 p14 = pp[(size_t)S3_.z*64]; short4 p15 = pp[(size_t)S3_.w*64];                \
    d += (W0_.x+W0_.y+W0_.z+W0_.w) + (W1_.x+W1_.y+W1_.z+W1_.w)                           \
       + (W2_.x+W2_.y+W2_.z+W2_.w) + (W3_.x+W3_.y+W3_.z+W3_.w);                          \
    acc0 += W0_.x*bf2f(p0.x)+W0_.y*bf2f(p1.x)+W0_.z*bf2f(p2.x)+W0_.w*bf2f(p3.x);         \
    acc1 += W0_.x*bf2f(p0.y)+W0_.y*bf2f(p1.y)+W0_.z*bf2f(p2.y)+W0_.w*bf2f(p3.y);         \
    acc2 += W0_.x*bf2f(p0.z)+W0_.y*bf2f(p1.z)+W0_.z*bf2f(p2.z)+W0_.w*bf2f(p3.z);         \
    acc3 += W0_.x*bf2f(p0.w)+W0_.y*bf2f(p1.w)+W0_.z*bf2f(p2.w)+W0_.w*bf2f(p3.w);         \
    acc0 += W1_.x*bf2f(p4.x)+W1_.y*bf2f(p5.x)+W1_.z*bf2f(p6.x)+W1_.w*bf2f(p7.x);         \
    acc1 += W1_.x*bf2f(p4.y)+W1_.y*bf2f(p5.y)+W1_.z*bf2f(p6.y)+W1_.w*bf2f(p7.y);         \
    acc2 += W1_.x*bf2f(p4.z)+W1_.y*bf2f(p5.z)+W1_.z*bf2f(p6.z)+W1_.w*bf2f(p7.z);         \
    acc3 += W1_.x*bf2f(p4.w)+W1_.y*bf2f(p5.w)+W1_.z*bf2f(p6.w)+W1_.w*bf2f(p7.w);         \
    acc0 += W2_.x*bf2f(p8.x)+W2_.y*bf2f(p9.x)+W2_.z*bf2f(p10.x)+W2_.w*bf2f(p11.x);       \
    acc1 += W2_.x*bf2f(p8.y)+W2_.y*bf2f(p9.y)+W2_.z*bf2f(p10.y)+W2_.w*bf2f(p11.y);       \
    acc2 += W2_.x*bf2f(p8.z)+W2_.y*bf2f(p9.z)+W2_.z*bf2f(p10.z)+W2_.w*bf2f(p11.z);       \
    acc3 += W2_.x*bf2f(p8.w)+W2_.y*bf2f(p9.w)+W2_.z*bf2f(p10.w)+W2_.w*bf2f(p11.w);       \
    acc0 += W3_.x*bf2f(p12.x)+W3_.y*bf2f(p13.x)+W3_.z*bf2f(p14.x)+W3_.w*bf2f(p15.x);     \
    acc1 += W3_.x*bf2f(p12.y)+W3_.y*bf2f(p13.y)+W3_.z*bf2f(p14.y)+W3_.w*bf2f(p15.y);     \
    acc2 += W3_.x*bf2f(p12.z)+W3_.y*bf2f(p13.z)+W3_.z*bf2f(p14.z)+W3_.w*bf2f(p15.z);     \
    acc3 += W3_.x*bf2f(p12.w)+W3_.y*bf2f(p13.w)+W3_.z*bf2f(p14.w)+W3_.w*bf2f(p15.w);     \
  }

// ---------------- single-pass fused attention (bf16 proj gather, no max-subtraction) ----------------
// Two-phase per 16-edge segment, no cross-lane shuffles.
//  Phase A (scores): lane=(edge j4=lane&15, head-quad g=lane>>4), one f32x4 s_src gather
//    covers 4 heads; w -> LDS wbuf[head][edge] (stride 20 -> 2-way banks = free).
//  Phase B (aggregate): full segments take the fast path — all 16 proj gathers issued
//    back-to-back (one latency exposure per node instead of four), then FMAs.
//    Denominator summed per-lane from the LDS w row: zero cross-lane shuffles.
template<int LN>
__global__ __launch_bounds__(256, 4)
void k_attn16(const int* __restrict__ row_start, const int2* __restrict__ es,
              const float* __restrict__ s_src, const float* __restrict__ s_tgt,
              const float* __restrict__ cvec,
              const short* __restrict__ projb, const short* __restrict__ skipb,
              const float* __restrict__ bias,
              const float* __restrict__ ln_g, const float* __restrict__ ln_b,
              short* __restrict__ houtb, int N){
  __shared__ __align__(16) float wbuf[4][16][20];   // [wave][head][edge(16)+pad]
  __shared__ __align__(16) int   svbuf[4][16];
  const int lane = threadIdx.x & 63;
  const int wave = threadIdx.x >> 6;
  const int node = blockIdx.x*4 + wave;
  if (node >= N) return;
  const int beg = row_start[node], end = row_start[node+1];

  const int h2 = lane >> 2;      // head owning this lane's 4 features (aggregation)
  const int j4 = lane & 15;      // edge slot (score phase)
  const int g  = lane >> 4;      // head-quad (score phase)

  const f32x4 stg = *(const f32x4*)(s_tgt + (size_t)node*16 + g*4);
  const f32x4 cg  = *(const f32x4*)(cvec + g*4);

  float d = 0.f;
  float acc0 = 0.f, acc1 = 0.f, acc2 = 0.f, acc3 = 0.f;

  for (int s0 = beg; s0 < end; s0 += 16){
    int cnt = end - s0; if (cnt > 16) cnt = 16;
    // ---- Phase A: scores for 16 edges x 16 heads ----
    int i  = s0 + j4;
    bool valid = (i < end);
    int ic = valid ? i : (end - 1);
    int2 e2 = es[ic];
    int sv = e2.x;
    float tp = __int_as_float(e2.y);
    f32x4 rv = *(const f32x4*)(s_src + (size_t)sv*16 + g*4);
    if (g == 0) svbuf[wave][j4] = sv;
    #pragma unroll
    for (int k = 0; k < 4; k++){
      float e = rv[k] + stg[k] + tp*cg[k];
      e = (e > 0.f) ? e : 0.2f*e;
      float w = valid ? __expf(e) : 0.f;
      wbuf[wave][g*4 + k][j4] = w;
    }
    // ---- Phase B ----
    if (cnt == 16){
      f32x4 wA = *(const f32x4*)&wbuf[wave][h2][0];
      f32x4 wB = *(const f32x4*)&wbuf[wave][h2][4];
      f32x4 wC = *(const f32x4*)&wbuf[wave][h2][8];
      f32x4 wD = *(const f32x4*)&wbuf[wave][h2][12];
      i32x4 sA = *(const i32x4*)&svbuf[wave][0];
      i32x4 sB = *(const i32x4*)&svbuf[wave][4];
      i32x4 sC = *(const i32x4*)&svbuf[wave][8];
      i32x4 sD = *(const i32x4*)&svbuf[wave][12];
      AGG16(wA, wB, wC, wD, sA, sB, sC, sD);
    } else {
      for (int j = 0; j < cnt; j += 4){
        f32x4 w4  = *(const f32x4*)&wbuf[wave][h2][j];
        i32x4 sv4 = *(const i32x4*)&svbuf[wave][j];
        short4 p0 = ((const short4*)(projb + (size_t)sv4.x*256))[lane];
        short4 p1 = ((const short4*)(projb + (size_t)sv4.y*256))[lane];
        short4 p2 = ((const short4*)(projb + (size_t)sv4.z*256))[lane];
        short4 p3 = ((const short4*)(projb + (size_t)sv4.w*256))[lane];
        d += (w4.x + w4.y) + (w4.z + w4.w);
        acc0 += w4.x*bf2f(p0.x) + w4.y*bf2f(p1.x) + w4.z*bf2f(p2.x) + w4.w*bf2f(p3.x);
        acc1 += w4.x*bf2f(p0.y) + w4.y*bf2f(p1.y) + w4.z*bf2f(p2.y) + w4.w*bf2f(p3.y);
        acc2 += w4.x*bf2f(p0.z) + w4.y*bf2f(p1.z) + w4.z*bf2f(p2.z) + w4.w*bf2f(p3.z);
        acc3 += w4.x*bf2f(p0.w) + w4.y*bf2f(p1.w) + w4.z*bf2f(p2.w) + w4.w*bf2f(p3.w);
      }
    }
  }
  float inv = 1.f / (d + 1e-16f);

  short4 sk = ((const short4*)(skipb + (size_t)node*256))[lane];
  float acc[4];
  acc[0] = acc0*inv + bf2f(sk.x); acc[1] = acc1*inv + bf2f(sk.y);
  acc[2] = acc2*inv + bf2f(sk.z); acc[3] = acc3*inv + bf2f(sk.w);

  #pragma unroll
  for (int j = 0; j < 4; j++){
    float v = acc[j] + bias[lane*4 + j];
    acc[j] = (v > 0.f) ? v : (__expf(v) - 1.f);
  }
  if (LN){
    float s  = acc[0] + acc[1] + acc[2] + acc[3];
    float s2 = acc[0]*acc[0] + acc[1]*acc[1] + acc[2]*acc[2] + acc[3]*acc[3];
    for (int o = 32; o > 0; o >>= 1){ s += __shfl_xor(s, o); s2 += __shfl_xor(s2, o); }
    float mu  = s * (1.f/256.f);
    float var = s2 * (1.f/256.f) - mu*mu;
    float rs  = rsqrtf(var + 1e-5f);
    #pragma unroll
    for (int j = 0; j < 4; j++)
      acc[j] = (acc[j] - mu)*rs*ln_g[lane*4 + j] + ln_b[lane*4 + j];
  }
  short4 ub; ub.x = f2bf(acc[0]); ub.y = f2bf(acc[1]);
  ub.z = f2bf(acc[2]); ub.w = f2bf(acc[3]);
  ((short4*)(houtb + (size_t)node*256))[lane] = ub;
}

// NH=1 variant: Phase A scores 64 edges (one per lane) into LDS; Phase B aggregates
// in 16-edge fully-unrolled blocks (w/sv broadcast ds_reads, free). No shuffles.
__global__ __launch_bounds__(256, 4)
void k_attn1(const int* __restrict__ row_start, const int2* __restrict__ es,
             const float* __restrict__ s_src, const float* __restrict__ s_tgt,
             const float* __restrict__ cvec,
             const short* __restrict__ projb, const short* __restrict__ skipb,
             const float* __restrict__ bias,
             const float* __restrict__ ln_g, const float* __restrict__ ln_b,
             short* __restrict__ houtb, int N){
  __shared__ __align__(16) float wb1[4][64];
  __shared__ __align__(16) int   sb1[4][64];
  const int lane = threadIdx.x & 63;
  const int wave = threadIdx.x >> 6;
  const int node = blockIdx.x*4 + wave;
  if (node >= N) return;
  const int beg = row_start[node], end = row_start[node+1];

  const float c0 = cvec[0];
  const float st = s_tgt[node];
  float d = 0.f;
  float acc0 = 0.f, acc1 = 0.f, acc2 = 0.f, acc3 = 0.f;

  for (int s0 = beg; s0 < end; s0 += 64){
    int cnt = end - s0; if (cnt > 64) cnt = 64;
    // ---- Phase A: one edge per lane ----
    int i  = s0 + lane;
    bool valid = (i < end);
    int ic = valid ? i : (end - 1);
    int2 e2 = es[ic];
    int sv = e2.x;
    float e = s_src[sv] + st + __int_as_float(e2.y)*c0;
    e = (e > 0.f) ? e : 0.2f*e;
    float w = valid ? __expf(e) : 0.f;
    wb1[wave][lane] = w;
    sb1[wave][lane] = sv;
    // ---- Phase B: 16-edge unrolled blocks, then 4-chunk tail (pads carry w=0) ----
    int bb = 0;
    for (; bb + 16 <= cnt; bb += 16){
      f32x4 wA = *(const f32x4*)&wb1[wave][bb+0];
      f32x4 wB = *(const f32x4*)&wb1[wave][bb+4];
      f32x4 wC = *(const f32x4*)&wb1[wave][bb+8];
      f32x4 wD = *(const f32x4*)&wb1[wave][bb+12];
      i32x4 sA = *(const i32x4*)&sb1[wave][bb+0];
      i32x4 sB = *(const i32x4*)&sb1[wave][bb+4];
      i32x4 sC = *(const i32x4*)&sb1[wave][bb+8];
      i32x4 sD = *(const i32x4*)&sb1[wave][bb+12];
      AGG16(wA, wB, wC, wD, sA, sB, sC, sD);
    }
    for (; bb < cnt; bb += 4){
      f32x4 w4  = *(const f32x4*)&wb1[wave][bb];
      i32x4 sv4 = *(const i32x4*)&sb1[wave][bb];
      short4 p0 = ((const short4*)(projb + (size_t)sv4.x*256))[lane];
      short4 p1 = ((const short4*)(projb + (size_t)sv4.y*256))[lane];
      short4 p2 = ((const short4*)(projb + (size_t)sv4.z*256))[lane];
      short4 p3 = ((const short4*)(projb + (size_t)sv4.w*256))[lane];
      d += (w4.x + w4.y) + (w4.z + w4.w);
      acc0 += w4.x*bf2f(p0.x) + w4.y*bf2f(p1.x) + w4.z*bf2f(p2.x) + w4.w*bf2f(p3.x);
      acc1 += w4.x*bf2f(p0.y) + w4.y*bf2f(p1.y) + w4.z*bf2f(p2.y) + w4.w*bf2f(p3.y);
      acc2 += w4.x*bf2f(p0.z) + w4.y*bf2f(p1.z) + w4.z*bf2f(p2.z) + w4.w*bf2f(p3.z);
      acc3 += w4.x*bf2f(p0.w) + w4.y*bf2f(p1.w) + w4.z*bf2f(p2.w) + w4.w*bf2f(p3.w);
    }
  }
  float inv = 1.f / (d + 1e-16f);

  short4 sk = ((const short4*)(skipb + (size_t)node*256))[lane];
  float acc[4];
  acc[0] = acc0*inv + bf2f(sk.x); acc[1] = acc1*inv + bf2f(sk.y);
  acc[2] = acc2*inv + bf2f(sk.z); acc[3] = acc3*inv + bf2f(sk.w);

  #pragma unroll
  for (int j = 0; j < 4; j++){
    float v = acc[j] + bias[lane*4 + j];
    acc[j] = (v > 0.f) ? v : (__expf(v) - 1.f);
  }
  float s  = acc[0] + acc[1] + acc[2] + acc[3];
  float s2 = acc[0]*acc[0] + acc[1]*acc[1] + acc[2]*acc[2] + acc[3]*acc[3];
  for (int o = 32; o > 0; o >>= 1){ s += __shfl_xor(s, o); s2 += __shfl_xor(s2, o); }
  float mu  = s * (1.f/256.f);
  float var = s2 * (1.f/256.f) - mu*mu;
  float rs  = rsqrtf(var + 1e-5f);
  #pragma unroll
  for (int j = 0; j < 4; j++)
    acc[j] = (acc[j] - mu)*rs*ln_g[lane*4 + j] + ln_b[lane*4 + j];
  short4 ub; ub.x = f2bf(acc[0]); ub.y = f2bf(acc[1]);
  ub.z = f2bf(acc[2]); ub.w = f2bf(acc[3]);
  ((short4*)(houtb + (size_t)node*256))[lane] = ub;
}

// ---------------- final gather (bf16 h -> fp32 out) ----------------
__global__ void k_gather(const short* hb, const int* x, float* out, int R){
  int r = blockIdx.x, t = threadIdx.x;
  if (r >= R) return;
  out[(size_t)r*256 + t] = bf2f(hb[(size_t)x[r]*256 + t]);
}

extern "C" void kernel_launch(void* const* d_in, const int* in_sizes, int n_in,
                              void* d_out, int out_size, void* d_ws, size_t ws_size,
                              hipStream_t stream){
  const int N = in_sizes[0] / 128;   // 50000
  const int E = in_sizes[1] / 2;     // 800000
  const int R = in_sizes[3];         // 8192

  const float* nf    = (const float*)d_in[0];
  const int*   ei    = (const int*)d_in[1];
  const float* eprob = (const float*)d_in[2];
  const int*   xidx  = (const int*)d_in[3];
  const float* W0     = (const float*)d_in[4];
  const float* a_src0 = (const float*)d_in[5];
  const float* a_tgt0 = (const float*)d_in[6];
  const float* Wtp0   = (const float*)d_in[7];
  const float* a_tp0  = (const float*)d_in[8];
  const float* Wskip0 = (const float*)d_in[9];
  const float* b0     = (const float*)d_in[10];
  const float* W1     = (const float*)d_in[11];
  const float* a_src1 = (const float*)d_in[12];
  const float* a_tgt1 = (const float*)d_in[13];
  const float* Wtp1   = (const float*)d_in[14];
  const float* a_tp1  = (const float*)d_in[15];
  const float* Wskip1 = (const float*)d_in[16];
  const float* b1     = (const float*)d_in[17];
  const float* ln1_g  = (const float*)d_in[18];
  const float* ln1_b  = (const float*)d_in[19];
  const float* W2     = (const float*)d_in[20];
  const float* a_src2 = (const float*)d_in[21];
  const float* a_tgt2 = (const float*)d_in[22];
  const float* Wtp2   = (const float*)d_in[23];
  const float* a_tp2  = (const float*)d_in[24];
  const float* b2     = (const float*)d_in[25];
  const float* ln2_g  = (const float*)d_in[26];
  const float* ln2_b  = (const float*)d_in[27];

  // ---- workspace layout (~103 MB) ----
  char* ws = (char*)d_ws;
  size_t off = 0;
  auto alloc = [&](size_t bytes)->char*{
    char* p = ws + off; off = (off + bytes + 255) & ~(size_t)255; return p;
  };
  short* Pb        = (short*)alloc((size_t)N*256*2);   // proj, bf16 (per layer)
  short* hXb       = (short*)alloc((size_t)N*256*2);   // bf16 h: L0 out, then L1 out
  short* Skb       = (short*)alloc((size_t)N*256*2);   // skip GEMM out (L0/L1), then final h
  short* nfb       = (short*)alloc((size_t)N*128*2);   // bf16 node features
  float* s_src     = (float*)alloc((size_t)N*16*4);
  float* s_tgt     = (float*)alloc((size_t)N*16*4);
  float* cvec      = (float*)alloc(256);
  int*   counts    = (int*)alloc((size_t)N*4);
  int*   row_start = (int*)alloc((size_t)(N+1)*4);
  int*   partials  = (int*)alloc(256*4);
  int2*  es        = (int2*)alloc((size_t)E*8);        // packed (src, tp) sorted by tgt
  short* W0t       = (short*)alloc((size_t)128*256*2);
  short* Ws0t      = (short*)alloc((size_t)128*256*2);
  short* W1t       = (short*)alloc((size_t)256*256*2);
  short* Ws1t      = (short*)alloc((size_t)256*256*2);
  short* W2t       = (short*)alloc((size_t)256*256*2);
  (void)ws_size; (void)n_in; (void)out_size;

  const int* src = ei;
  const int* tgt = ei + E;

  // ---- prep: weight transposes + nf convert + cvecs ----
  k_wt<<<(256*128+255)/256, 256, 0, stream>>>(W0,     W0t,  128);
  k_wt<<<(256*128+255)/256, 256, 0, stream>>>(Wskip0, Ws0t, 128);
  k_wt<<<(256*256+255)/256, 256, 0, stream>>>(W1,     W1t,  256);
  k_wt<<<(256*256+255)/256, 256, 0, stream>>>(Wskip1, Ws1t, 256);
  k_wt<<<(256*256+255)/256, 256, 0, stream>>>(W2,     W2t,  256);
  k_cvt<<<((N*128/4)+255)/256, 256, 0, stream>>>(nf, nfb, N*128/4);
  k_cvec<<<1, 256, 0, stream>>>(Wtp0, a_tp0, cvec + 0,  16);
  k_cvec<<<1, 256, 0, stream>>>(Wtp1, a_tp1, cvec + 16, 16);
  k_cvec<<<1, 256, 0, stream>>>(Wtp2, a_tp2, cvec + 32, 1);

  // ---- CSR build ----
  k_zero<<<(N+255)/256, 256, 0, stream>>>(counts, N);
  k_hist<<<(E+255)/256, 256, 0, stream>>>(tgt, counts, E);
  int NB = (N + 1023) / 1024;
  k_scan1<<<NB, 1024, 0, stream>>>(counts, row_start, partials, N);
  k_scan2<<<1, 64, 0, stream>>>(partials, NB);
  k_scan3<<<(N+255)/256, 256, 0, stream>>>(row_start, partials, counts, N, E);
  k_scatter<<<(E+255)/256, 256, 0, stream>>>(src, tgt, eprob, counts, es, E);

  const int gt = (N + 63) / 64;   // GEMM m-tiles
  const int at = (N + 3) / 4;     // attn blocks (4 waves each)

  // ---- Layer 0: GAT(128 -> 16x16 concat), skip = nf @ Wskip0, ELU, no LN ----
  k_gemm_lds<4><<<dim3(gt,2), 256, 0, stream>>>(nfb, W0t, Ws0t, Pb, Skb,
                                                a_src0, a_tgt0, s_src, s_tgt, N);
  k_attn16<0><<<at, 256, 0, stream>>>(row_start, es, s_src, s_tgt, cvec + 0,
                                      Pb, Skb, b0, nullptr, nullptr, hXb, N);

  // ---- Layer 1: GAT(256 -> 16x16 concat), skip = h @ Wskip1, ELU, LN ----
  k_gemm_lds<8><<<dim3(gt,2), 256, 0, stream>>>(hXb, W1t, Ws1t, Pb, Skb,
                                                a_src1, a_tgt1, s_src, s_tgt, N);
  k_attn16<1><<<at, 256, 0, stream>>>(row_start, es, s_src, s_tgt, cvec + 16,
                                      Pb, Skb, b1, ln1_g, ln1_b, hXb, N);

  // ---- Layer 2: GAT(256 -> 1x256, avg = identity), identity skip, ELU, LN ----
  k_gemm_lds<8><<<dim3(gt,1), 256, 0, stream>>>(hXb, W2t, nullptr, Pb, nullptr,
                                                nullptr, nullptr, nullptr, nullptr, N);
  k_svec1<<<at, 256, 0, stream>>>(Pb, a_src2, a_tgt2, s_src, s_tgt, N);
  k_attn1<<<at, 256, 0, stream>>>(row_start, es, s_src, s_tgt, cvec + 32,
                                  Pb, hXb, b2, ln2_g, ln2_b, Skb, N);

  // ---- gather rows into output (fp32) ----
  k_gather<<<R, 256, 0, stream>>>(Skb, xidx, (float*)d_out, R);
}

// Round 3
// 548.666 us; speedup vs baseline: 1.0140x; 1.0140x over previous
//
#include <hip/hip_runtime.h>
#include <hip/hip_fp16.h>
#include <math.h>

typedef __attribute__((ext_vector_type(8))) short    s16x8;   // 8 fp16 (4 VGPRs)
typedef __attribute__((ext_vector_type(8))) _Float16 h16x8;   // MFMA f16 operand
typedef __attribute__((ext_vector_type(4))) float    f32x4;   // MFMA accumulator
typedef __attribute__((ext_vector_type(4))) int      i32x4;
typedef __attribute__((ext_vector_type(4))) unsigned u32x4;

__device__ __forceinline__ short f2h(float x){ return __half_as_short(__float2half(x)); }
__device__ __forceinline__ float h2f(short s){ return __half2float(__short_as_half(s)); }
__device__ __forceinline__ __half2 u2h2(unsigned u){
  union { unsigned u; __half2 h; } c; c.u = u; return c.h;
}

// ---------------- fp32 -> fp16 convert (n % 4 == 0) ----------------
__global__ void k_cvt(const float* __restrict__ in, short* __restrict__ outb, int n4){
  int i = blockIdx.x*blockDim.x + threadIdx.x;
  if (i >= n4) return;
  float4 v = ((const float4*)in)[i];
  short4 u; u.x = f2h(v.x); u.y = f2h(v.y); u.z = f2h(v.z); u.w = f2h(v.w);
  ((short4*)outb)[i] = u;
}

// ---------------- weight transpose+convert: Wt[n][k] (fp16) from W[k][n] (fp32) ----------------
__global__ void k_wt(const float* W, short* Wt, int K){
  int idx = blockIdx.x*blockDim.x + threadIdx.x;
  if (idx >= 256*K) return;
  int n = idx / K, k = idx - n*K;
  Wt[idx] = f2h(W[(size_t)k*256 + n]);
}

// c[h] = sum_f Wtp[h*F+f]*a_tp[h*F+f]
__global__ void k_cvec(const float* Wtp, const float* a_tp, float* c, int NH){
  __shared__ float buf[256];
  int t = threadIdx.x;
  buf[t] = Wtp[t] * a_tp[t];
  __syncthreads();
  int F = 256 / NH;
  if (t < NH){
    float s = 0.f;
    for (int f = 0; f < F; f++) s += buf[t*F + f];
    c[t] = s;
  }
}

// ---------------- CSR build (sort edges by target) ----------------
__global__ void k_zero(int* p, int n){
  int i = blockIdx.x*blockDim.x + threadIdx.x;
  if (i < n) p[i] = 0;
}
__global__ void k_hist(const int* tgt, int* counts, int E){
  int i = blockIdx.x*blockDim.x + threadIdx.x;
  if (i < E) atomicAdd(&counts[tgt[i]], 1);
}
__global__ void k_scan1(const int* counts, int* row_excl, int* partials, int N){
  __shared__ int buf[1024];
  int t = threadIdx.x; int i = blockIdx.x*1024 + t;
  int v = (i < N) ? counts[i] : 0;
  buf[t] = v; __syncthreads();
  for (int o = 1; o < 1024; o <<= 1){
    int x = (t >= o) ? buf[t-o] : 0;
    __syncthreads();
    buf[t] += x;
    __syncthreads();
  }
  if (i < N) row_excl[i] = buf[t] - v;
  if (t == 1023) partials[blockIdx.x] = buf[1023];
}
__global__ void k_scan2(int* partials, int NB){
  if (threadIdx.x == 0 && blockIdx.x == 0){
    int s = 0;
    for (int b = 0; b < NB; b++){ int v = partials[b]; partials[b] = s; s += v; }
  }
}
__global__ void k_scan3(int* row_start, const int* partials, int* cursor, int N, int E){
  int i = blockIdx.x*blockDim.x + threadIdx.x;
  if (i < N){
    int v = row_start[i] + partials[i >> 10];
    row_start[i] = v; cursor[i] = v;
  }
  if (i == 0) row_start[N] = E;
}
// pack (src, transition_prob) as int2 for one 8B load per edge in attention
__global__ void k_scatter(const int* src, const int* tgt, const float* eprob,
                          int* cursor, int2* es, int E){
  int i = blockIdx.x*blockDim.x + threadIdx.x;
  if (i >= E) return;
  int tg = tgt[i];
  int p = atomicAdd(&cursor[tg], 1);
  int2 v; v.x = src[i]; v.y = __float_as_int(eprob[i]);
  es[p] = v;
}

// ---------------- LDS-staged MFMA GEMM (fp16) ----------------
// y=0: proj -> fp16 C1b + fused s_src/s_tgt (NH=16, from fp32 accs; skip if asrc null).
// y=1: skip -> fp16 C2b.
template<int KC>   // K/32 chunks: 4 (K=128) or 8 (K=256)
__global__ __launch_bounds__(256)
void k_gemm_lds(const short* __restrict__ Ab,
                const short* __restrict__ B1t, const short* __restrict__ B2t,
                short* __restrict__ C1b, short* __restrict__ C2b,
                const float* __restrict__ asrc, const float* __restrict__ atgt,
                float* __restrict__ s_src, float* __restrict__ s_tgt, int M){
  const int K = KC*32;
  __shared__ short lA[64*32];     // 4 KB
  __shared__ short lB[256*32];    // 16 KB
  const int tid  = threadIdx.x;
  const int lane = tid & 63;
  const int wave = tid >> 6;
  const int m16  = lane & 15;
  const int q    = lane >> 4;
  const int swz  = (m16 >> 1) & 3;
  const int r0   = blockIdx.x * 64;
  const bool first = (blockIdx.y == 0);
  const short* __restrict__ Bt = first ? B1t : B2t;
  short* __restrict__ Cb = first ? C1b : C2b;

  int arow = r0 + (tid >> 2); if (arow >= M) arow = M - 1;
  const int akq = (tid & 3) ^ ((tid >> 3) & 3);
  int bn[4], bkq[4];
  #pragma unroll
  for (int j = 0; j < 4; j++){
    int sj = j*256 + tid;
    bn[j]  = sj >> 2;
    bkq[j] = (sj & 3) ^ ((sj >> 3) & 3);
  }

  f32x4 acc[4][4];
  #pragma unroll
  for (int mi = 0; mi < 4; mi++)
    #pragma unroll
    for (int ni = 0; ni < 4; ni++) acc[mi][ni] = {0.f,0.f,0.f,0.f};

  s16x8 ra = *(const s16x8*)(Ab + (size_t)arow*K + akq*8);
  s16x8 rb[4];
  #pragma unroll
  for (int j = 0; j < 4; j++)
    rb[j] = *(const s16x8*)(Bt + (size_t)bn[j]*K + bkq[j]*8);

  for (int c = 0; c < KC; c++){
    __syncthreads();
    *(s16x8*)(lA + tid*8) = ra;
    #pragma unroll
    for (int j = 0; j < 4; j++)
      *(s16x8*)(lB + (j*256 + tid)*8) = rb[j];
    __syncthreads();

    if (c + 1 < KC){
      int k0 = (c+1)*32;
      ra = *(const s16x8*)(Ab + (size_t)arow*K + k0 + akq*8);
      #pragma unroll
      for (int j = 0; j < 4; j++)
        rb[j] = *(const s16x8*)(Bt + (size_t)bn[j]*K + k0 + bkq[j]*8);
    }

    s16x8 Af[4], Bf[4];
    #pragma unroll
    for (int mi = 0; mi < 4; mi++){
      int slot = (mi*16 + m16)*4 + (q ^ swz);
      Af[mi] = *(const s16x8*)(lA + slot*8);
    }
    #pragma unroll
    for (int ni = 0; ni < 4; ni++){
      int n = wave*64 + ni*16 + m16;
      int slot = n*4 + (q ^ swz);
      Bf[ni] = *(const s16x8*)(lB + slot*8);
    }
    #pragma unroll
    for (int mi = 0; mi < 4; mi++)
      #pragma unroll
      for (int ni = 0; ni < 4; ni++)
        acc[mi][ni] = __builtin_amdgcn_mfma_f32_16x16x32_f16(
            *(h16x8*)&Bf[ni], *(h16x8*)&Af[mi], acc[mi][ni], 0, 0, 0);
  }

  #pragma unroll
  for (int mi = 0; mi < 4; mi++){
    int row = r0 + mi*16 + m16;
    bool ok = (row < M);
    #pragma unroll
    for (int ni = 0; ni < 4; ni++){
      if (ok){
        size_t o = (size_t)row*256 + wave*64 + ni*16 + q*4;
        short4 u; u.x = f2h(acc[mi][ni][0]); u.y = f2h(acc[mi][ni][1]);
        u.z = f2h(acc[mi][ni][2]); u.w = f2h(acc[mi][ni][3]);
        *(short4*)(Cb + o) = u;
      }
      if (first && asrc){
        // fused svec: head hh = wave*4+ni; lane holds features q*4..q*4+3 of row
        int hh = wave*4 + ni;
        const float* as = asrc + hh*16 + q*4;
        const float* at = atgt + hh*16 + q*4;
        float pss = acc[mi][ni][0]*as[0] + acc[mi][ni][1]*as[1]
                  + acc[mi][ni][2]*as[2] + acc[mi][ni][3]*as[3];
        float pst = acc[mi][ni][0]*at[0] + acc[mi][ni][1]*at[1]
                  + acc[mi][ni][2]*at[2] + acc[mi][ni][3]*at[3];
        pss += __shfl_xor(pss, 16); pss += __shfl_xor(pss, 32);
        pst += __shfl_xor(pst, 16); pst += __shfl_xor(pst, 32);
        if (ok && q == 0){
          s_src[row*16 + hh] = pss;
          s_tgt[row*16 + hh] = pst;
        }
      }
    }
  }
}

// ---------------- NH=1 score projections from fp16 proj (wave per node) ----------------
__global__ void k_svec1(const short* __restrict__ Pb,
                        const float* __restrict__ a_src, const float* __restrict__ a_tgt,
                        float* __restrict__ s_src, float* __restrict__ s_tgt, int N){
  int lane = threadIdx.x & 63;
  int node = blockIdx.x*(blockDim.x >> 6) + (threadIdx.x >> 6);
  if (node >= N) return;
  short4 p = ((const short4*)(Pb + (size_t)node*256))[lane];
  const float* as = a_src + lane*4;
  const float* at = a_tgt + lane*4;
  float f0 = h2f(p.x), f1 = h2f(p.y), f2 = h2f(p.z), f3 = h2f(p.w);
  float ss = f0*as[0] + f1*as[1] + f2*as[2] + f3*as[3];
  float st = f0*at[0] + f1*at[1] + f2*at[2] + f3*at[3];
  for (int o = 32; o > 0; o >>= 1){ ss += __shfl_xor(ss, o); st += __shfl_xor(st, o); }
  if (lane == 0){ s_src[node] = ss; s_tgt[node] = st; }
}

// ---------------- single-pass fused attention, NH=16 (packed-fp16 aggregation) ----------------
// Two-phase per 16-edge segment, no cross-lane shuffles.
//  Phase A (scores): lane=(edge j4=lane&15, head-quad g=lane>>4), one f32x4 s_src gather
//    covers 4 heads; w stored as DUPLICATED fp16 pair (one uint) -> LDS wpk[head][edge].
//  Phase B (aggregate): per 4-edge chunk: uint4 w read (2-way banks, free), broadcast sv
//    read, 4 uint2 proj gathers; 3 __hfma2 per edge (features lo/hi + denominator).
//    fp16 accumulators are flushed to f32 each segment (bounds error, no overflow:
//    layer-0/1 scores are 16-dim dots, w <= ~50, segment sums << fp16 max).
template<int LN>
__global__ __launch_bounds__(256)
void k_attn16(const int* __restrict__ row_start, const int2* __restrict__ es,
              const float* __restrict__ s_src, const float* __restrict__ s_tgt,
              const float* __restrict__ cvec,
              const short* __restrict__ projb, const short* __restrict__ skipb,
              const float* __restrict__ bias,
              const float* __restrict__ ln_g, const float* __restrict__ ln_b,
              short* __restrict__ houtb, int N){
  __shared__ __align__(16) unsigned wpk[4][16][20];   // [wave][head][edge(16)+pad]
  __shared__ __align__(16) int      svbuf[4][16];
  const int lane = threadIdx.x & 63;
  const int wave = threadIdx.x >> 6;
  const int node = blockIdx.x*4 + wave;
  if (node >= N) return;
  const int beg = row_start[node], end = row_start[node+1];

  const int h2 = lane >> 2;      // head owning this lane's 4 features (aggregation)
  const int j4 = lane & 15;      // edge slot (score phase)
  const int g  = lane >> 4;      // head-quad (score phase)

  const f32x4 stg = *(const f32x4*)(s_tgt + (size_t)node*16 + g*4);
  const f32x4 cg  = *(const f32x4*)(cvec + g*4);
  const __half2 kOne = u2h2(0x3C003C00u);

  float d = 0.f;
  float facc0 = 0.f, facc1 = 0.f, facc2 = 0.f, facc3 = 0.f;

  for (int s0 = beg; s0 < end; s0 += 16){
    int cnt = end - s0; if (cnt > 16) cnt = 16;
    // ---- Phase A: scores for 16 edges x 16 heads ----
    int i  = s0 + j4;
    bool valid = (i < end);
    int ic = valid ? i : (end - 1);
    int2 e2 = es[ic];
    int sv = e2.x;
    float tp = __int_as_float(e2.y);
    f32x4 rv = *(const f32x4*)(s_src + (size_t)sv*16 + g*4);
    if (g == 0) svbuf[wave][j4] = sv;
    #pragma unroll
    for (int k = 0; k < 4; k++){
      float e = rv[k] + stg[k] + tp*cg[k];
      e = (e > 0.f) ? e : 0.2f*e;
      float w = valid ? __expf(e) : 0.f;
      unsigned hb = (unsigned)__half_as_ushort(__float2half(w));
      wpk[wave][g*4 + k][j4] = (hb << 16) | hb;
    }
    // ---- Phase B: packed fp16 accumulate over this segment ----
    __half2 a01 = u2h2(0u), a23 = u2h2(0u), dpk = u2h2(0u);
    const uint2* __restrict__ pp = (const uint2*)projb + lane;
    for (int j = 0; j < cnt; j += 4){
      u32x4 wq  = *(const u32x4*)&wpk[wave][h2][j];
      i32x4 sv4 = *(const i32x4*)&svbuf[wave][j];
      uint2 p0 = pp[(size_t)sv4.x*64];
      uint2 p1 = pp[(size_t)sv4.y*64];
      uint2 p2 = pp[(size_t)sv4.z*64];
      uint2 p3 = pp[(size_t)sv4.w*64];
      __half2 w0 = u2h2(wq.x), w1 = u2h2(wq.y), w2 = u2h2(wq.z), w3 = u2h2(wq.w);
      dpk = __hfma2(w0, kOne, dpk); dpk = __hfma2(w1, kOne, dpk);
      dpk = __hfma2(w2, kOne, dpk); dpk = __hfma2(w3, kOne, dpk);
      a01 = __hfma2(w0, u2h2(p0.x), a01); a23 = __hfma2(w0, u2h2(p0.y), a23);
      a01 = __hfma2(w1, u2h2(p1.x), a01); a23 = __hfma2(w1, u2h2(p1.y), a23);
      a01 = __hfma2(w2, u2h2(p2.x), a01); a23 = __hfma2(w2, u2h2(p2.y), a23);
      a01 = __hfma2(w3, u2h2(p3.x), a01); a23 = __hfma2(w3, u2h2(p3.y), a23);
    }
    facc0 += __low2float(a01); facc1 += __high2float(a01);
    facc2 += __low2float(a23); facc3 += __high2float(a23);
    d += __low2float(dpk);
  }
  float inv = 1.f / (d + 1e-16f);

  short4 sk = ((const short4*)(skipb + (size_t)node*256))[lane];
  float acc[4];
  acc[0] = facc0*inv + h2f(sk.x); acc[1] = facc1*inv + h2f(sk.y);
  acc[2] = facc2*inv + h2f(sk.z); acc[3] = facc3*inv + h2f(sk.w);

  #pragma unroll
  for (int j = 0; j < 4; j++){
    float v = acc[j] + bias[lane*4 + j];
    acc[j] = (v > 0.f) ? v : (__expf(v) - 1.f);
  }
  if (LN){
    float s  = acc[0] + acc[1] + acc[2] + acc[3];
    float s2 = acc[0]*acc[0] + acc[1]*acc[1] + acc[2]*acc[2] + acc[3]*acc[3];
    for (int o = 32; o > 0; o >>= 1){ s += __shfl_xor(s, o); s2 += __shfl_xor(s2, o); }
    float mu  = s * (1.f/256.f);
    float var = s2 * (1.f/256.f) - mu*mu;
    float rs  = rsqrtf(var + 1e-5f);
    #pragma unroll
    for (int j = 0; j < 4; j++)
      acc[j] = (acc[j] - mu)*rs*ln_g[lane*4 + j] + ln_b[lane*4 + j];
  }
  short4 ub; ub.x = f2h(acc[0]); ub.y = f2h(acc[1]);
  ub.z = f2h(acc[2]); ub.w = f2h(acc[3]);
  ((short4*)(houtb + (size_t)node*256))[lane] = ub;
}

// NH=1 variant: f32 scalar math retained (layer-2 scores are 256-dim dots; w = exp(e)
// can reach ~e^11 which overflows fp16 — do NOT pack here without a shift).
__global__ __launch_bounds__(256)
void k_attn1(const int* __restrict__ row_start, const int2* __restrict__ es,
             const float* __restrict__ s_src, const float* __restrict__ s_tgt,
             const float* __restrict__ cvec,
             const short* __restrict__ projb, const short* __restrict__ skipb,
             const float* __restrict__ bias,
             const float* __restrict__ ln_g, const float* __restrict__ ln_b,
             short* __restrict__ houtb, int N){
  __shared__ __align__(16) float wb1[4][64];
  __shared__ __align__(16) int   sb1[4][64];
  const int lane = threadIdx.x & 63;
  const int wave = threadIdx.x >> 6;
  const int node = blockIdx.x*4 + wave;
  if (node >= N) return;
  const int beg = row_start[node], end = row_start[node+1];

  const float c0 = cvec[0];
  const float st = s_tgt[node];
  float d = 0.f;
  float acc0 = 0.f, acc1 = 0.f, acc2 = 0.f, acc3 = 0.f;

  for (int s0 = beg; s0 < end; s0 += 64){
    int cnt = end - s0; if (cnt > 64) cnt = 64;
    // ---- Phase A: one edge per lane ----
    int i  = s0 + lane;
    bool valid = (i < end);
    int ic = valid ? i : (end - 1);
    int2 e2 = es[ic];
    int sv = e2.x;
    float e = s_src[sv] + st + __int_as_float(e2.y)*c0;
    e = (e > 0.f) ? e : 0.2f*e;
    float w = valid ? __expf(e) : 0.f;
    wb1[wave][lane] = w;
    sb1[wave][lane] = sv;
    // ---- Phase B: 4-edge chunks (pads carry w=0, sv clamped) ----
    for (int j = 0; j < cnt; j += 4){
      f32x4 w4  = *(const f32x4*)&wb1[wave][j];
      i32x4 sv4 = *(const i32x4*)&sb1[wave][j];
      short4 p0 = ((const short4*)(projb + (size_t)sv4.x*256))[lane];
      short4 p1 = ((const short4*)(projb + (size_t)sv4.y*256))[lane];
      short4 p2 = ((const short4*)(projb + (size_t)sv4.z*256))[lane];
      short4 p3 = ((const short4*)(projb + (size_t)sv4.w*256))[lane];
      d += (w4.x + w4.y) + (w4.z + w4.w);
      acc0 += w4.x*h2f(p0.x) + w4.y*h2f(p1.x) + w4.z*h2f(p2.x) + w4.w*h2f(p3.x);
      acc1 += w4.x*h2f(p0.y) + w4.y*h2f(p1.y) + w4.z*h2f(p2.y) + w4.w*h2f(p3.y);
      acc2 += w4.x*h2f(p0.z) + w4.y*h2f(p1.z) + w4.z*h2f(p2.z) + w4.w*h2f(p3.z);
      acc3 += w4.x*h2f(p0.w) + w4.y*h2f(p1.w) + w4.z*h2f(p2.w) + w4.w*h2f(p3.w);
    }
  }
  float inv = 1.f / (d + 1e-16f);

  short4 sk = ((const short4*)(skipb + (size_t)node*256))[lane];
  float acc[4];
  acc[0] = acc0*inv + h2f(sk.x); acc[1] = acc1*inv + h2f(sk.y);
  acc[2] = acc2*inv + h2f(sk.z); acc[3] = acc3*inv + h2f(sk.w);

  #pragma unroll
  for (int j = 0; j < 4; j++){
    float v = acc[j] + bias[lane*4 + j];
    acc[j] = (v > 0.f) ? v : (__expf(v) - 1.f);
  }
  float s  = acc[0] + acc[1] + acc[2] + acc[3];
  float s2 = acc[0]*acc[0] + acc[1]*acc[1] + acc[2]*acc[2] + acc[3]*acc[3];
  for (int o = 32; o > 0; o >>= 1){ s += __shfl_xor(s, o); s2 += __shfl_xor(s2, o); }
  float mu  = s * (1.f/256.f);
  float var = s2 * (1.f/256.f) - mu*mu;
  float rs  = rsqrtf(var + 1e-5f);
  #pragma unroll
  for (int j = 0; j < 4; j++)
    acc[j] = (acc[j] - mu)*rs*ln_g[lane*4 + j] + ln_b[lane*4 + j];
  short4 ub; ub.x = f2h(acc[0]); ub.y = f2h(acc[1]);
  ub.z = f2h(acc[2]); ub.w = f2h(acc[3]);
  ((short4*)(houtb + (size_t)node*256))[lane] = ub;
}

// ---------------- final gather (fp16 h -> fp32 out) ----------------
__global__ void k_gather(const short* hb, const int* x, float* out, int R){
  int r = blockIdx.x, t = threadIdx.x;
  if (r >= R) return;
  out[(size_t)r*256 + t] = h2f(hb[(size_t)x[r]*256 + t]);
}

extern "C" void kernel_launch(void* const* d_in, const int* in_sizes, int n_in,
                              void* d_out, int out_size, void* d_ws, size_t ws_size,
                              hipStream_t stream){
  const int N = in_sizes[0] / 128;   // 50000
  const int E = in_sizes[1] / 2;     // 800000
  const int R = in_sizes[3];         // 8192

  const float* nf    = (const float*)d_in[0];
  const int*   ei    = (const int*)d_in[1];
  const float* eprob = (const float*)d_in[2];
  const int*   xidx  = (const int*)d_in[3];
  const float* W0     = (const float*)d_in[4];
  const float* a_src0 = (const float*)d_in[5];
  const float* a_tgt0 = (const float*)d_in[6];
  const float* Wtp0   = (const float*)d_in[7];
  const float* a_tp0  = (const float*)d_in[8];
  const float* Wskip0 = (const float*)d_in[9];
  const float* b0     = (const float*)d_in[10];
  const float* W1     = (const float*)d_in[11];
  const float* a_src1 = (const float*)d_in[12];
  const float* a_tgt1 = (const float*)d_in[13];
  const float* Wtp1   = (const float*)d_in[14];
  const float* a_tp1  = (const float*)d_in[15];
  const float* Wskip1 = (const float*)d_in[16];
  const float* b1     = (const float*)d_in[17];
  const float* ln1_g  = (const float*)d_in[18];
  const float* ln1_b  = (const float*)d_in[19];
  const float* W2     = (const float*)d_in[20];
  const float* a_src2 = (const float*)d_in[21];
  const float* a_tgt2 = (const float*)d_in[22];
  const float* Wtp2   = (const float*)d_in[23];
  const float* a_tp2  = (const float*)d_in[24];
  const float* b2     = (const float*)d_in[25];
  const float* ln2_g  = (const float*)d_in[26];
  const float* ln2_b  = (const float*)d_in[27];

  // ---- workspace layout (~103 MB) ----
  char* ws = (char*)d_ws;
  size_t off = 0;
  auto alloc = [&](size_t bytes)->char*{
    char* p = ws + off; off = (off + bytes + 255) & ~(size_t)255; return p;
  };
  short* Pb        = (short*)alloc((size_t)N*256*2);   // proj, fp16 (per layer)
  short* hXb       = (short*)alloc((size_t)N*256*2);   // fp16 h: L0 out, then L1 out
  short* Skb       = (short*)alloc((size_t)N*256*2);   // skip GEMM out (L0/L1), then final h
  short* nfb       = (short*)alloc((size_t)N*128*2);   // fp16 node features
  float* s_src     = (float*)alloc((size_t)N*16*4);
  float* s_tgt     = (float*)alloc((size_t)N*16*4);
  float* cvec      = (float*)alloc(256);
  int*   counts    = (int*)alloc((size_t)N*4);
  int*   row_start = (int*)alloc((size_t)(N+1)*4);
  int*   partials  = (int*)alloc(256*4);
  int2*  es        = (int2*)alloc((size_t)E*8);        // packed (src, tp) sorted by tgt
  short* W0t       = (short*)alloc((size_t)128*256*2);
  short* Ws0t      = (short*)alloc((size_t)128*256*2);
  short* W1t       = (short*)alloc((size_t)256*256*2);
  short* Ws1t      = (short*)alloc((size_t)256*256*2);
  short* W2t       = (short*)alloc((size_t)256*256*2);
  (void)ws_size; (void)n_in; (void)out_size;

  const int* src = ei;
  const int* tgt = ei + E;

  // ---- prep: weight transposes + nf convert + cvecs ----
  k_wt<<<(256*128+255)/256, 256, 0, stream>>>(W0,     W0t,  128);
  k_wt<<<(256*128+255)/256, 256, 0, stream>>>(Wskip0, Ws0t, 128);
  k_wt<<<(256*256+255)/256, 256, 0, stream>>>(W1,     W1t,  256);
  k_wt<<<(256*256+255)/256, 256, 0, stream>>>(Wskip1, Ws1t, 256);
  k_wt<<<(256*256+255)/256, 256, 0, stream>>>(W2,     W2t,  256);
  k_cvt<<<((N*128/4)+255)/256, 256, 0, stream>>>(nf, nfb, N*128/4);
  k_cvec<<<1, 256, 0, stream>>>(Wtp0, a_tp0, cvec + 0,  16);
  k_cvec<<<1, 256, 0, stream>>>(Wtp1, a_tp1, cvec + 16, 16);
  k_cvec<<<1, 256, 0, stream>>>(Wtp2, a_tp2, cvec + 32, 1);

  // ---- CSR build ----
  k_zero<<<(N+255)/256, 256, 0, stream>>>(counts, N);
  k_hist<<<(E+255)/256, 256, 0, stream>>>(tgt, counts, E);
  int NB = (N + 1023) / 1024;
  k_scan1<<<NB, 1024, 0, stream>>>(counts, row_start, partials, N);
  k_scan2<<<1, 64, 0, stream>>>(partials, NB);
  k_scan3<<<(N+255)/256, 256, 0, stream>>>(row_start, partials, counts, N, E);
  k_scatter<<<(E+255)/256, 256, 0, stream>>>(src, tgt, eprob, counts, es, E);

  const int gt = (N + 63) / 64;   // GEMM m-tiles
  const int at = (N + 3) / 4;     // attn blocks (4 waves each)

  // ---- Layer 0: GAT(128 -> 16x16 concat), skip = nf @ Wskip0, ELU, no LN ----
  k_gemm_lds<4><<<dim3(gt,2), 256, 0, stream>>>(nfb, W0t, Ws0t, Pb, Skb,
                                                a_src0, a_tgt0, s_src, s_tgt, N);
  k_attn16<0><<<at, 256, 0, stream>>>(row_start, es, s_src, s_tgt, cvec + 0,
                                      Pb, Skb, b0, nullptr, nullptr, hXb, N);

  // ---- Layer 1: GAT(256 -> 16x16 concat), skip = h @ Wskip1, ELU, LN ----
  k_gemm_lds<8><<<dim3(gt,2), 256, 0, stream>>>(hXb, W1t, Ws1t, Pb, Skb,
                                                a_src1, a_tgt1, s_src, s_tgt, N);
  k_attn16<1><<<at, 256, 0, stream>>>(row_start, es, s_src, s_tgt, cvec + 16,
                                      Pb, Skb, b1, ln1_g, ln1_b, hXb, N);

  // ---- Layer 2: GAT(256 -> 1x256, avg = identity), identity skip, ELU, LN ----
  k_gemm_lds<8><<<dim3(gt,1), 256, 0, stream>>>(hXb, W2t, nullptr, Pb, nullptr,
                                                nullptr, nullptr, nullptr, nullptr, N);
  k_svec1<<<at, 256, 0, stream>>>(Pb, a_src2, a_tgt2, s_src, s_tgt, N);
  k_attn1<<<at, 256, 0, stream>>>(row_start, es, s_src, s_tgt, cvec + 32,
                                  Pb, hXb, b2, ln2_g, ln2_b, Skb, N);

  // ---- gather rows into output (fp32) ----
  k_gather<<<R, 256, 0, stream>>>(Skb, xidx, (float*)d_out, R);
}

// Round 5
// 524.488 us; speedup vs baseline: 1.0608x; 1.0461x over previous
//
#include <hip/hip_runtime.h>
#include <hip/hip_fp16.h>
#include <math.h>

typedef __attribute__((ext_vector_type(8))) short    s16x8;   // 8 fp16 (4 VGPRs)
typedef __attribute__((ext_vector_type(8))) _Float16 h16x8;   // MFMA f16 operand
typedef __attribute__((ext_vector_type(4))) float    f32x4;   // MFMA accumulator
typedef __attribute__((ext_vector_type(4))) int      i32x4;

__device__ __forceinline__ short f2h(float x){ return __half_as_short(__float2half(x)); }
__device__ __forceinline__ float h2f(short s){ return __half2float(__short_as_half(s)); }

// ---------------- fp32 -> fp16 convert (n % 4 == 0) ----------------
__global__ void k_cvt(const float* __restrict__ in, short* __restrict__ outb, int n4){
  int i = blockIdx.x*blockDim.x + threadIdx.x;
  if (i >= n4) return;
  float4 v = ((const float4*)in)[i];
  short4 u; u.x = f2h(v.x); u.y = f2h(v.y); u.z = f2h(v.z); u.w = f2h(v.w);
  ((short4*)outb)[i] = u;
}

// ---------------- weight transpose+convert: Wt[n][k] (fp16) from W[k][n] (fp32) ----------------
__global__ void k_wt(const float* W, short* Wt, int K){
  int idx = blockIdx.x*blockDim.x + threadIdx.x;
  if (idx >= 256*K) return;
  int n = idx / K, k = idx - n*K;
  Wt[idx] = f2h(W[(size_t)k*256 + n]);
}

// c[h] = sum_f Wtp[h*F+f]*a_tp[h*F+f]
__global__ void k_cvec(const float* Wtp, const float* a_tp, float* c, int NH){
  __shared__ float buf[256];
  int t = threadIdx.x;
  buf[t] = Wtp[t] * a_tp[t];
  __syncthreads();
  int F = 256 / NH;
  if (t < NH){
    float s = 0.f;
    for (int f = 0; f < F; f++) s += buf[t*F + f];
    c[t] = s;
  }
}

// ---------------- CSR build (sort edges by target) ----------------
__global__ void k_zero(int* p, int n){
  int i = blockIdx.x*blockDim.x + threadIdx.x;
  if (i < n) p[i] = 0;
}
__global__ void k_hist(const int* tgt, int* counts, int E){
  int i = blockIdx.x*blockDim.x + threadIdx.x;
  if (i < E) atomicAdd(&counts[tgt[i]], 1);
}
__global__ void k_scan1(const int* counts, int* row_excl, int* partials, int N){
  __shared__ int buf[1024];
  int t = threadIdx.x; int i = blockIdx.x*1024 + t;
  int v = (i < N) ? counts[i] : 0;
  buf[t] = v; __syncthreads();
  for (int o = 1; o < 1024; o <<= 1){
    int x = (t >= o) ? buf[t-o] : 0;
    __syncthreads();
    buf[t] += x;
    __syncthreads();
  }
  if (i < N) row_excl[i] = buf[t] - v;
  if (t == 1023) partials[blockIdx.x] = buf[1023];
}
__global__ void k_scan2(int* partials, int NB){
  if (threadIdx.x == 0 && blockIdx.x == 0){
    int s = 0;
    for (int b = 0; b < NB; b++){ int v = partials[b]; partials[b] = s; s += v; }
  }
}
__global__ void k_scan3(int* row_start, const int* partials, int* cursor, int N, int E){
  int i = blockIdx.x*blockDim.x + threadIdx.x;
  if (i < N){
    int v = row_start[i] + partials[i >> 10];
    row_start[i] = v; cursor[i] = v;
  }
  if (i == 0) row_start[N] = E;
}
// pack (src, transition_prob) as int2 for one 8B load per edge in attention
__global__ void k_scatter(const int* src, const int* tgt, const float* eprob,
                          int* cursor, int2* es, int E){
  int i = blockIdx.x*blockDim.x + threadIdx.x;
  if (i >= E) return;
  int tg = tgt[i];
  int p = atomicAdd(&cursor[tg], 1);
  int2 v; v.x = src[i]; v.y = __float_as_int(eprob[i]);
  es[p] = v;
}

// ---------------- LDS-staged MFMA GEMM (fp16 in, fp16/int8 out) ----------------
// y=0: proj -> fp16 C1b (if non-null) and/or per-row-scaled int8 C8+pscale (if non-null)
//      + fused s_src/s_tgt (NH=16, from fp32 accs; skip if asrc null).
// y=1: skip -> fp16 C2b.
template<int KC>   // K/32 chunks: 4 (K=128) or 8 (K=256)
__global__ __launch_bounds__(256)
void k_gemm_lds(const short* __restrict__ Ab,
                const short* __restrict__ B1t, const short* __restrict__ B2t,
                short* __restrict__ C1b, short* __restrict__ C2b,
                unsigned char* __restrict__ C8, float* __restrict__ pscale,
                const float* __restrict__ asrc, const float* __restrict__ atgt,
                float* __restrict__ s_src, float* __restrict__ s_tgt, int M){
  const int K = KC*32;
  __shared__ short lA[64*32];     // 4 KB
  __shared__ short lB[256*32];    // 16 KB
  const int tid  = threadIdx.x;
  const int lane = tid & 63;
  const int wave = tid >> 6;
  const int m16  = lane & 15;
  const int q    = lane >> 4;
  const int swz  = (m16 >> 1) & 3;
  const int r0   = blockIdx.x * 64;
  const bool first = (blockIdx.y == 0);
  const short* __restrict__ Bt = first ? B1t : B2t;
  short* __restrict__ Cb = first ? C1b : C2b;

  int arow = r0 + (tid >> 2); if (arow >= M) arow = M - 1;
  const int akq = (tid & 3) ^ ((tid >> 3) & 3);
  int bn[4], bkq[4];
  #pragma unroll
  for (int j = 0; j < 4; j++){
    int sj = j*256 + tid;
    bn[j]  = sj >> 2;
    bkq[j] = (sj & 3) ^ ((sj >> 3) & 3);
  }

  f32x4 acc[4][4];
  #pragma unroll
  for (int mi = 0; mi < 4; mi++)
    #pragma unroll
    for (int ni = 0; ni < 4; ni++) acc[mi][ni] = {0.f,0.f,0.f,0.f};

  s16x8 ra = *(const s16x8*)(Ab + (size_t)arow*K + akq*8);
  s16x8 rb[4];
  #pragma unroll
  for (int j = 0; j < 4; j++)
    rb[j] = *(const s16x8*)(Bt + (size_t)bn[j]*K + bkq[j]*8);

  for (int c = 0; c < KC; c++){
    __syncthreads();
    *(s16x8*)(lA + tid*8) = ra;
    #pragma unroll
    for (int j = 0; j < 4; j++)
      *(s16x8*)(lB + (j*256 + tid)*8) = rb[j];
    __syncthreads();

    if (c + 1 < KC){
      int k0 = (c+1)*32;
      ra = *(const s16x8*)(Ab + (size_t)arow*K + k0 + akq*8);
      #pragma unroll
      for (int j = 0; j < 4; j++)
        rb[j] = *(const s16x8*)(Bt + (size_t)bn[j]*K + k0 + bkq[j]*8);
    }

    s16x8 Af[4], Bf[4];
    #pragma unroll
    for (int mi = 0; mi < 4; mi++){
      int slot = (mi*16 + m16)*4 + (q ^ swz);
      Af[mi] = *(const s16x8*)(lA + slot*8);
    }
    #pragma unroll
    for (int ni = 0; ni < 4; ni++){
      int n = wave*64 + ni*16 + m16;
      int slot = n*4 + (q ^ swz);
      Bf[ni] = *(const s16x8*)(lB + slot*8);
    }
    #pragma unroll
    for (int mi = 0; mi < 4; mi++)
      #pragma unroll
      for (int ni = 0; ni < 4; ni++)
        acc[mi][ni] = __builtin_amdgcn_mfma_f32_16x16x32_f16(
            *(h16x8*)&Bf[ni], *(h16x8*)&Af[mi], acc[mi][ni], 0, 0, 0);
  }

  #pragma unroll
  for (int mi = 0; mi < 4; mi++){
    int row = r0 + mi*16 + m16;
    bool ok = (row < M);
    #pragma unroll
    for (int ni = 0; ni < 4; ni++){
      if (ok && Cb){
        size_t o = (size_t)row*256 + wave*64 + ni*16 + q*4;
        short4 u; u.x = f2h(acc[mi][ni][0]); u.y = f2h(acc[mi][ni][1]);
        u.z = f2h(acc[mi][ni][2]); u.w = f2h(acc[mi][ni][3]);
        *(short4*)(Cb + o) = u;
      }
      if (first && asrc){
        // fused svec: head hh = wave*4+ni; lane holds features q*4..q*4+3 of row
        int hh = wave*4 + ni;
        const float* as = asrc + hh*16 + q*4;
        const float* at = atgt + hh*16 + q*4;
        float pss = acc[mi][ni][0]*as[0] + acc[mi][ni][1]*as[1]
                  + acc[mi][ni][2]*as[2] + acc[mi][ni][3]*as[3];
        float pst = acc[mi][ni][0]*at[0] + acc[mi][ni][1]*at[1]
                  + acc[mi][ni][2]*at[2] + acc[mi][ni][3]*at[3];
        pss += __shfl_xor(pss, 16); pss += __shfl_xor(pss, 32);
        pst += __shfl_xor(pst, 16); pst += __shfl_xor(pst, 32);
        if (ok && q == 0){
          s_src[row*16 + hh] = pss;
          s_tgt[row*16 + hh] = pst;
        }
      }
    }
  }

  // ---- per-row-scaled int8 encode (layers 0/1 message proj) ----
  if (first && C8){
    // row max |x| over 256 cols: reduce over k,ni (in-lane), q (shfl), waves (LDS)
    float am[4];
    #pragma unroll
    for (int mi = 0; mi < 4; mi++){
      float a = 0.f;
      #pragma unroll
      for (int ni = 0; ni < 4; ni++)
        #pragma unroll
        for (int k = 0; k < 4; k++)
          a = fmaxf(a, fabsf(acc[mi][ni][k]));
      a = fmaxf(a, __shfl_xor(a, 16));
      a = fmaxf(a, __shfl_xor(a, 32));
      am[mi] = a;
    }
    __syncthreads();                      // all waves done reading lA/lB
    float* rmax = (float*)lA;             // [wave][64 rows] = 1 KB, reuse lA
    if (q == 0){
      #pragma unroll
      for (int mi = 0; mi < 4; mi++) rmax[wave*64 + mi*16 + m16] = am[mi];
    }
    __syncthreads();
    #pragma unroll
    for (int mi = 0; mi < 4; mi++){
      int r = mi*16 + m16;
      int row = r0 + r;
      bool ok = (row < M);
      float s = fmaxf(fmaxf(rmax[r], rmax[64+r]), fmaxf(rmax[128+r], rmax[192+r]));
      float scl = s * (1.f/127.f);
      float inv = (s > 0.f) ? (127.f/s) : 0.f;
      if (ok && wave == 0 && q == 0) pscale[row] = scl;
      if (ok){
        #pragma unroll
        for (int ni = 0; ni < 4; ni++){
          int v0 = __float2int_rn(acc[mi][ni][0]*inv) + 128;
          int v1 = __float2int_rn(acc[mi][ni][1]*inv) + 128;
          int v2 = __float2int_rn(acc[mi][ni][2]*inv) + 128;
          int v3 = __float2int_rn(acc[mi][ni][3]*inv) + 128;
          unsigned pk = (unsigned)(v0 & 255) | ((unsigned)(v1 & 255) << 8)
                      | ((unsigned)(v2 & 255) << 16) | ((unsigned)(v3 & 255) << 24);
          *(unsigned*)(C8 + (size_t)row*256 + wave*64 + ni*16 + q*4) = pk;
        }
      }
    }
  }
}

// ---------------- NH=1 score projections from fp16 proj (wave per node) ----------------
__global__ void k_svec1(const short* __restrict__ Pb,
                        const float* __restrict__ a_src, const float* __restrict__ a_tgt,
                        float* __restrict__ s_src, float* __restrict__ s_tgt, int N){
  int lane = threadIdx.x & 63;
  int node = blockIdx.x*(blockDim.x >> 6) + (threadIdx.x >> 6);
  if (node >= N) return;
  short4 p = ((const short4*)(Pb + (size_t)node*256))[lane];
  const float* as = a_src + lane*4;
  const float* at = a_tgt + lane*4;
  float f0 = h2f(p.x), f1 = h2f(p.y), f2 = h2f(p.z), f3 = h2f(p.w);
  float ss = f0*as[0] + f1*as[1] + f2*as[2] + f3*as[3];
  float st = f0*at[0] + f1*at[1] + f2*at[2] + f3*at[3];
  for (int o = 32; o > 0; o >>= 1){ ss += __shfl_xor(ss, o); st += __shfl_xor(st, o); }
  if (lane == 0){ s_src[node] = ss; s_tgt[node] = st; }
}

// ---------------- single-pass fused attention, NH=16 (int8 proj gather) ----------------
// Two-phase per 16-edge segment, no cross-lane shuffles.
//  Phase A (scores): lane=(edge j4=lane&15, head-quad g=lane>>4), one f32x4 s_src gather
//    covers 4 heads; w (f32) -> LDS wbuf[head][edge] (stride 20 -> 2-way banks = free);
//    g==0 lanes also stage pscale[sv] per edge.
//  Phase B (aggregate): per 4-edge chunk: w f32x4 + scale f32x4 + sv i32x4 LDS reads,
//    4 proj gathers of ONE uint each (4 biased-u8 features); decode via cvt_f32_ubyte,
//    accumulate acc += (w*scale)*u with running dws = sum(w*scale); bias correction
//    acc -= 128*dws folded once at the end. Gather row = 256 B (half of fp16).
template<int LN>
__global__ __launch_bounds__(256)
void k_attn16(const int* __restrict__ row_start, const int2* __restrict__ es,
              const float* __restrict__ s_src, const float* __restrict__ s_tgt,
              const float* __restrict__ cvec,
              const unsigned char* __restrict__ proj8, const float* __restrict__ pscale,
              const short* __restrict__ skipb,
              const float* __restrict__ bias,
              const float* __restrict__ ln_g, const float* __restrict__ ln_b,
              short* __restrict__ houtb, int N){
  __shared__ __align__(16) float wbuf[4][16][20];   // [wave][head][edge(16)+pad]
  __shared__ __align__(16) int   svbuf[4][16];
  __shared__ __align__(16) float scbuf[4][16];
  const int lane = threadIdx.x & 63;
  const int wave = threadIdx.x >> 6;
  const int node = blockIdx.x*4 + wave;
  if (node >= N) return;
  const int beg = row_start[node], end = row_start[node+1];

  const int h2 = lane >> 2;      // head owning this lane's 4 features (aggregation)
  const int j4 = lane & 15;      // edge slot (score phase)
  const int g  = lane >> 4;      // head-quad (score phase)

  const f32x4 stg = *(const f32x4*)(s_tgt + (size_t)node*16 + g*4);
  const f32x4 cg  = *(const f32x4*)(cvec + g*4);

  float d = 0.f, dws = 0.f;
  float acc0 = 0.f, acc1 = 0.f, acc2 = 0.f, acc3 = 0.f;

  for (int s0 = beg; s0 < end; s0 += 16){
    int cnt = end - s0; if (cnt > 16) cnt = 16;
    // ---- Phase A: scores for 16 edges x 16 heads ----
    int i  = s0 + j4;
    bool valid = (i < end);
    int ic = valid ? i : (end - 1);
    int2 e2 = es[ic];
    int sv = e2.x;
    float tp = __int_as_float(e2.y);
    f32x4 rv = *(const f32x4*)(s_src + (size_t)sv*16 + g*4);
    if (g == 0){ svbuf[wave][j4] = sv; scbuf[wave][j4] = pscale[sv]; }
    #pragma unroll
    for (int k = 0; k < 4; k++){
      float e = rv[k] + stg[k] + tp*cg[k];
      e = (e > 0.f) ? e : 0.2f*e;
      wbuf[wave][g*4 + k][j4] = valid ? __expf(e) : 0.f;
    }
    // ---- Phase B: int8 gather + f32 accumulate (pads carry w=0, sv clamped) ----
    const unsigned* __restrict__ pp = (const unsigned*)proj8 + lane;
    for (int j = 0; j < cnt; j += 4){
      f32x4 w4  = *(const f32x4*)&wbuf[wave][h2][j];
      f32x4 sc4 = *(const f32x4*)&scbuf[wave][j];
      i32x4 sv4 = *(const i32x4*)&svbuf[wave][j];
      unsigned q0 = pp[(size_t)sv4.x*64];
      unsigned q1 = pp[(size_t)sv4.y*64];
      unsigned q2 = pp[(size_t)sv4.z*64];
      unsigned q3 = pp[(size_t)sv4.w*64];
      float ws0 = w4.x*sc4.x, ws1 = w4.y*sc4.y, ws2 = w4.z*sc4.z, ws3 = w4.w*sc4.w;
      d   += (w4.x + w4.y) + (w4.z + w4.w);
      dws += (ws0 + ws1) + (ws2 + ws3);
      acc0 += ws0*(float)(q0 & 255) + ws1*(float)(q1 & 255)
            + ws2*(float)(q2 & 255) + ws3*(float)(q3 & 255);
      acc1 += ws0*(float)((q0 >> 8) & 255) + ws1*(float)((q1 >> 8) & 255)
            + ws2*(float)((q2 >> 8) & 255) + ws3*(float)((q3 >> 8) & 255);
      acc2 += ws0*(float)((q0 >> 16) & 255) + ws1*(float)((q1 >> 16) & 255)
            + ws2*(float)((q2 >> 16) & 255) + ws3*(float)((q3 >> 16) & 255);
      acc3 += ws0*(float)(q0 >> 24) + ws1*(float)(q1 >> 24)
            + ws2*(float)(q2 >> 24) + ws3*(float)(q3 >> 24);
    }
  }
  float inv = 1.f / (d + 1e-16f);
  float c128 = 128.f * dws;

  short4 sk = ((const short4*)(skipb + (size_t)node*256))[lane];
  float acc[4];
  acc[0] = (acc0 - c128)*inv + h2f(sk.x); acc[1] = (acc1 - c128)*inv + h2f(sk.y);
  acc[2] = (acc2 - c128)*inv + h2f(sk.z); acc[3] = (acc3 - c128)*inv + h2f(sk.w);

  #pragma unroll
  for (int j = 0; j < 4; j++){
    float v = acc[j] + bias[lane*4 + j];
    acc[j] = (v > 0.f) ? v : (__expf(v) - 1.f);
  }
  if (LN){
    float s  = acc[0] + acc[1] + acc[2] + acc[3];
    float s2 = acc[0]*acc[0] + acc[1]*acc[1] + acc[2]*acc[2] + acc[3]*acc[3];
    for (int o = 32; o > 0; o >>= 1){ s += __shfl_xor(s, o); s2 += __shfl_xor(s2, o); }
    float mu  = s * (1.f/256.f);
    float var = s2 * (1.f/256.f) - mu*mu;
    float rs  = rsqrtf(var + 1e-5f);
    #pragma unroll
    for (int j = 0; j < 4; j++)
      acc[j] = (acc[j] - mu)*rs*ln_g[lane*4 + j] + ln_b[lane*4 + j];
  }
  short4 ub; ub.x = f2h(acc[0]); ub.y = f2h(acc[1]);
  ub.z = f2h(acc[2]); ub.w = f2h(acc[3]);
  ((short4*)(houtb + (size_t)node*256))[lane] = ub;
}

// NH=1 variant (layer 2, final): full fp16 proj kept for accuracy — the last layer's
// message error lands directly in the output, so no int8 here.
__global__ __launch_bounds__(256)
void k_attn1(const int* __restrict__ row_start, const int2* __restrict__ es,
             const float* __restrict__ s_src, const float* __restrict__ s_tgt,
             const float* __restrict__ cvec,
             const short* __restrict__ projb, const short* __restrict__ skipb,
             const float* __restrict__ bias,
             const float* __restrict__ ln_g, const float* __restrict__ ln_b,
             short* __restrict__ houtb, int N){
  __shared__ __align__(16) float wb1[4][64];
  __shared__ __align__(16) int   sb1[4][64];
  const int lane = threadIdx.x & 63;
  const int wave = threadIdx.x >> 6;
  const int node = blockIdx.x*4 + wave;
  if (node >= N) return;
  const int beg = row_start[node], end = row_start[node+1];

  const float c0 = cvec[0];
  const float st = s_tgt[node];
  float d = 0.f;
  float acc0 = 0.f, acc1 = 0.f, acc2 = 0.f, acc3 = 0.f;

  for (int s0 = beg; s0 < end; s0 += 64){
    int cnt = end - s0; if (cnt > 64) cnt = 64;
    // ---- Phase A: one edge per lane ----
    int i  = s0 + lane;
    bool valid = (i < end);
    int ic = valid ? i : (end - 1);
    int2 e2 = es[ic];
    int sv = e2.x;
    float e = s_src[sv] + st + __int_as_float(e2.y)*c0;
    e = (e > 0.f) ? e : 0.2f*e;
    float w = valid ? __expf(e) : 0.f;
    wb1[wave][lane] = w;
    sb1[wave][lane] = sv;
    // ---- Phase B: 4-edge chunks (pads carry w=0, sv clamped) ----
    for (int j = 0; j < cnt; j += 4){
      f32x4 w4  = *(const f32x4*)&wb1[wave][j];
      i32x4 sv4 = *(const i32x4*)&sb1[wave][j];
      short4 p0 = ((const short4*)(projb + (size_t)sv4.x*256))[lane];
      short4 p1 = ((const short4*)(projb + (size_t)sv4.y*256))[lane];
      short4 p2 = ((const short4*)(projb + (size_t)sv4.z*256))[lane];
      short4 p3 = ((const short4*)(projb + (size_t)sv4.w*256))[lane];
      d += (w4.x + w4.y) + (w4.z + w4.w);
      acc0 += w4.x*h2f(p0.x) + w4.y*h2f(p1.x) + w4.z*h2f(p2.x) + w4.w*h2f(p3.x);
      acc1 += w4.x*h2f(p0.y) + w4.y*h2f(p1.y) + w4.z*h2f(p2.y) + w4.w*h2f(p3.y);
      acc2 += w4.x*h2f(p0.z) + w4.y*h2f(p1.z) + w4.z*h2f(p2.z) + w4.w*h2f(p3.z);
      acc3 += w4.x*h2f(p0.w) + w4.y*h2f(p1.w) + w4.z*h2f(p2.w) + w4.w*h2f(p3.w);
    }
  }
  float inv = 1.f / (d + 1e-16f);

  short4 sk = ((const short4*)(skipb + (size_t)node*256))[lane];
  float acc[4];
  acc[0] = acc0*inv + h2f(sk.x); acc[1] = acc1*inv + h2f(sk.y);
  acc[2] = acc2*inv + h2f(sk.z); acc[3] = acc3*inv + h2f(sk.w);

  #pragma unroll
  for (int j = 0; j < 4; j++){
    float v = acc[j] + bias[lane*4 + j];
    acc[j] = (v > 0.f) ? v : (__expf(v) - 1.f);
  }
  float s  = acc[0] + acc[1] + acc[2] + acc[3];
  float s2 = acc[0]*acc[0] + acc[1]*acc[1] + acc[2]*acc[2] + acc[3]*acc[3];
  for (int o = 32; o > 0; o >>= 1){ s += __shfl_xor(s, o); s2 += __shfl_xor(s2, o); }
  float mu  = s * (1.f/256.f);
  float var = s2 * (1.f/256.f) - mu*mu;
  float rs  = rsqrtf(var + 1e-5f);
  #pragma unroll
  for (int j = 0; j < 4; j++)
    acc[j] = (acc[j] - mu)*rs*ln_g[lane*4 + j] + ln_b[lane*4 + j];
  short4 ub; ub.x = f2h(acc[0]); ub.y = f2h(acc[1]);
  ub.z = f2h(acc[2]); ub.w = f2h(acc[3]);
  ((short4*)(houtb + (size_t)node*256))[lane] = ub;
}

// ---------------- final gather (fp16 h -> fp32 out) ----------------
__global__ void k_gather(const short* hb, const int* x, float* out, int R){
  int r = blockIdx.x, t = threadIdx.x;
  if (r >= R) return;
  out[(size_t)r*256 + t] = h2f(hb[(size_t)x[r]*256 + t]);
}

extern "C" void kernel_launch(void* const* d_in, const int* in_sizes, int n_in,
                              void* d_out, int out_size, void* d_ws, size_t ws_size,
                              hipStream_t stream){
  const int N = in_sizes[0] / 128;   // 50000
  const int E = in_sizes[1] / 2;     // 800000
  const int R = in_sizes[3];         // 8192

  const float* nf    = (const float*)d_in[0];
  const int*   ei    = (const int*)d_in[1];
  const float* eprob = (const float*)d_in[2];
  const int*   xidx  = (const int*)d_in[3];
  const float* W0     = (const float*)d_in[4];
  const float* a_src0 = (const float*)d_in[5];
  const float* a_tgt0 = (const float*)d_in[6];
  const float* Wtp0   = (const float*)d_in[7];
  const float* a_tp0  = (const float*)d_in[8];
  const float* Wskip0 = (const float*)d_in[9];
  const float* b0     = (const float*)d_in[10];
  const float* W1     = (const float*)d_in[11];
  const float* a_src1 = (const float*)d_in[12];
  const float* a_tgt1 = (const float*)d_in[13];
  const float* Wtp1   = (const float*)d_in[14];
  const float* a_tp1  = (const float*)d_in[15];
  const float* Wskip1 = (const float*)d_in[16];
  const float* b1     = (const float*)d_in[17];
  const float* ln1_g  = (const float*)d_in[18];
  const float* ln1_b  = (const float*)d_in[19];
  const float* W2     = (const float*)d_in[20];
  const float* a_src2 = (const float*)d_in[21];
  const float* a_tgt2 = (const float*)d_in[22];
  const float* Wtp2   = (const float*)d_in[23];
  const float* a_tp2  = (const float*)d_in[24];
  const float* b2     = (const float*)d_in[25];
  const float* ln2_g  = (const float*)d_in[26];
  const float* ln2_b  = (const float*)d_in[27];

  // ---- workspace layout (~110 MB) ----
  char* ws = (char*)d_ws;
  size_t off = 0;
  auto alloc = [&](size_t bytes)->char*{
    char* p = ws + off; off = (off + bytes + 255) & ~(size_t)255; return p;
  };
  short* Pb        = (short*)alloc((size_t)N*256*2);   // proj, fp16 (layer 2)
  unsigned char* P8 = (unsigned char*)alloc((size_t)N*256);  // proj, int8 (layers 0/1)
  float* pscale    = (float*)alloc((size_t)N*4);       // per-row int8 scale
  short* hXb       = (short*)alloc((size_t)N*256*2);   // fp16 h: L0 out, then L1 out
  short* Skb       = (short*)alloc((size_t)N*256*2);   // skip GEMM out (L0/L1), then final h
  short* nfb       = (short*)alloc((size_t)N*128*2);   // fp16 node features
  float* s_src     = (float*)alloc((size_t)N*16*4);
  float* s_tgt     = (float*)alloc((size_t)N*16*4);
  float* cvec      = (float*)alloc(256);
  int*   counts    = (int*)alloc((size_t)N*4);
  int*   row_start = (int*)alloc((size_t)(N+1)*4);
  int*   partials  = (int*)alloc(256*4);
  int2*  es        = (int2*)alloc((size_t)E*8);        // packed (src, tp) sorted by tgt
  short* W0t       = (short*)alloc((size_t)128*256*2);
  short* Ws0t      = (short*)alloc((size_t)128*256*2);
  short* W1t       = (short*)alloc((size_t)256*256*2);
  short* Ws1t      = (short*)alloc((size_t)256*256*2);
  short* W2t       = (short*)alloc((size_t)256*256*2);
  (void)ws_size; (void)n_in; (void)out_size;

  const int* src = ei;
  const int* tgt = ei + E;

  // ---- prep: weight transposes + nf convert + cvecs ----
  k_wt<<<(256*128+255)/256, 256, 0, stream>>>(W0,     W0t,  128);
  k_wt<<<(256*128+255)/256, 256, 0, stream>>>(Wskip0, Ws0t, 128);
  k_wt<<<(256*256+255)/256, 256, 0, stream>>>(W1,     W1t,  256);
  k_wt<<<(256*256+255)/256, 256, 0, stream>>>(Wskip1, Ws1t, 256);
  k_wt<<<(256*256+255)/256, 256, 0, stream>>>(W2,     W2t,  256);
  k_cvt<<<((N*128/4)+255)/256, 256, 0, stream>>>(nf, nfb, N*128/4);
  k_cvec<<<1, 256, 0, stream>>>(Wtp0, a_tp0, cvec + 0,  16);
  k_cvec<<<1, 256, 0, stream>>>(Wtp1, a_tp1, cvec + 16, 16);
  k_cvec<<<1, 256, 0, stream>>>(Wtp2, a_tp2, cvec + 32, 1);

  // ---- CSR build ----
  k_zero<<<(N+255)/256, 256, 0, stream>>>(counts, N);
  k_hist<<<(E+255)/256, 256, 0, stream>>>(tgt, counts, E);
  int NB = (N + 1023) / 1024;
  k_scan1<<<NB, 1024, 0, stream>>>(counts, row_start, partials, N);
  k_scan2<<<1, 64, 0, stream>>>(partials, NB);
  k_scan3<<<(N+255)/256, 256, 0, stream>>>(row_start, partials, counts, N, E);
  k_scatter<<<(E+255)/256, 256, 0, stream>>>(src, tgt, eprob, counts, es, E);

  const int gt = (N + 63) / 64;   // GEMM m-tiles
  const int at = (N + 3) / 4;     // attn blocks (4 waves each)

  // ---- Layer 0: GAT(128 -> 16x16 concat), skip = nf @ Wskip0, ELU, no LN ----
  k_gemm_lds<4><<<dim3(gt,2), 256, 0, stream>>>(nfb, W0t, Ws0t, nullptr, Skb, P8, pscale,
                                                a_src0, a_tgt0, s_src, s_tgt, N);
  k_attn16<0><<<at, 256, 0, stream>>>(row_start, es, s_src, s_tgt, cvec + 0,
                                      P8, pscale, Skb, b0, nullptr, nullptr, hXb, N);

  // ---- Layer 1: GAT(256 -> 16x16 concat), skip = h @ Wskip1, ELU, LN ----
  k_gemm_lds<8><<<dim3(gt,2), 256, 0, stream>>>(hXb, W1t, Ws1t, nullptr, Skb, P8, pscale,
                                                a_src1, a_tgt1, s_src, s_tgt, N);
  k_attn16<1><<<at, 256, 0, stream>>>(row_start, es, s_src, s_tgt, cvec + 16,
                                      P8, pscale, Skb, b1, ln1_g, ln1_b, hXb, N);

  // ---- Layer 2: GAT(256 -> 1x256, avg = identity), identity skip, ELU, LN ----
  k_gemm_lds<8><<<dim3(gt,1), 256, 0, stream>>>(hXb, W2t, nullptr, Pb, nullptr,
                                                nullptr, nullptr,
                                                nullptr, nullptr, nullptr, nullptr, N);
  k_svec1<<<at, 256, 0, stream>>>(Pb, a_src2, a_tgt2, s_src, s_tgt, N);
  k_attn1<<<at, 256, 0, stream>>>(row_start, es, s_src, s_tgt, cvec + 32,
                                  Pb, hXb, b2, ln2_g, ln2_b, Skb, N);

  // ---- gather rows into output (fp32) ----
  k_gather<<<R, 256, 0, stream>>>(Skb, xidx, (float*)d_out, R);
}

// Round 6
// 502.413 us; speedup vs baseline: 1.1074x; 1.0439x over previous
//
#include <hip/hip_runtime.h>
#include <hip/hip_fp16.h>
#include <math.h>

typedef __attribute__((ext_vector_type(8))) short    s16x8;   // 8 fp16 (4 VGPRs)
typedef __attribute__((ext_vector_type(8))) _Float16 h16x8;   // MFMA f16 operand
typedef __attribute__((ext_vector_type(4))) float    f32x4;   // MFMA accumulator
typedef __attribute__((ext_vector_type(4))) int      i32x4;

__device__ __forceinline__ short f2h(float x){ return __half_as_short(__float2half(x)); }
__device__ __forceinline__ float h2f(short s){ return __half2float(__short_as_half(s)); }

// ---------------- fp32 -> fp16 convert (n % 4 == 0) ----------------
__global__ void k_cvt(const float* __restrict__ in, short* __restrict__ outb, int n4){
  int i = blockIdx.x*blockDim.x + threadIdx.x;
  if (i >= n4) return;
  float4 v = ((const float4*)in)[i];
  short4 u; u.x = f2h(v.x); u.y = f2h(v.y); u.z = f2h(v.z); u.w = f2h(v.w);
  ((short4*)outb)[i] = u;
}

// ---------------- weight transpose+convert: Wt[n][k] (fp16) from W[k][n] (fp32) ----------------
__global__ void k_wt(const float* W, short* Wt, int K){
  int idx = blockIdx.x*blockDim.x + threadIdx.x;
  if (idx >= 256*K) return;
  int n = idx / K, k = idx - n*K;
  Wt[idx] = f2h(W[(size_t)k*256 + n]);
}

// c[h] = sum_f Wtp[h*F+f]*a_tp[h*F+f]
__global__ void k_cvec(const float* Wtp, const float* a_tp, float* c, int NH){
  __shared__ float buf[256];
  int t = threadIdx.x;
  buf[t] = Wtp[t] * a_tp[t];
  __syncthreads();
  int F = 256 / NH;
  if (t < NH){
    float s = 0.f;
    for (int f = 0; f < F; f++) s += buf[t*F + f];
    c[t] = s;
  }
}

// ---------------- CSR build (sort edges by target) ----------------
__global__ void k_zero(int* p, int n){
  int i = blockIdx.x*blockDim.x + threadIdx.x;
  if (i < n) p[i] = 0;
}
__global__ void k_hist(const int* tgt, int* counts, int E){
  int i = blockIdx.x*blockDim.x + threadIdx.x;
  if (i < E) atomicAdd(&counts[tgt[i]], 1);
}
__global__ void k_scan1(const int* counts, int* row_excl, int* partials, int N){
  __shared__ int buf[1024];
  int t = threadIdx.x; int i = blockIdx.x*1024 + t;
  int v = (i < N) ? counts[i] : 0;
  buf[t] = v; __syncthreads();
  for (int o = 1; o < 1024; o <<= 1){
    int x = (t >= o) ? buf[t-o] : 0;
    __syncthreads();
    buf[t] += x;
    __syncthreads();
  }
  if (i < N) row_excl[i] = buf[t] - v;
  if (t == 1023) partials[blockIdx.x] = buf[1023];
}
__global__ void k_scan2(int* partials, int NB){
  if (threadIdx.x == 0 && blockIdx.x == 0){
    int s = 0;
    for (int b = 0; b < NB; b++){ int v = partials[b]; partials[b] = s; s += v; }
  }
}
__global__ void k_scan3(int* row_start, const int* partials, int* cursor, int N, int E){
  int i = blockIdx.x*blockDim.x + threadIdx.x;
  if (i < N){
    int v = row_start[i] + partials[i >> 10];
    row_start[i] = v; cursor[i] = v;
  }
  if (i == 0) row_start[N] = E;
}
// pack (src, transition_prob) as int2 for one 8B load per edge in attention
__global__ void k_scatter(const int* src, const int* tgt, const float* eprob,
                          int* cursor, int2* es, int E){
  int i = blockIdx.x*blockDim.x + threadIdx.x;
  if (i >= E) return;
  int tg = tgt[i];
  int p = atomicAdd(&cursor[tg], 1);
  int2 v; v.x = src[i]; v.y = __float_as_int(eprob[i]);
  es[p] = v;
}

// ---------------- LDS-staged MFMA GEMM (fp16 in, fp16/int8 out) ----------------
// y=0: proj -> fp16 C1b (if non-null) and/or per-row-scaled int8 C8+pscale (if non-null)
//      + fused s_src/s_tgt (NH=16, from fp32 accs; skip if asrc null).
// y=1: skip -> fp16 C2b.
template<int KC>   // K/32 chunks: 4 (K=128) or 8 (K=256)
__global__ __launch_bounds__(256)
void k_gemm_lds(const short* __restrict__ Ab,
                const short* __restrict__ B1t, const short* __restrict__ B2t,
                short* __restrict__ C1b, short* __restrict__ C2b,
                unsigned char* __restrict__ C8, float* __restrict__ pscale,
                const float* __restrict__ asrc, const float* __restrict__ atgt,
                float* __restrict__ s_src, float* __restrict__ s_tgt, int M){
  const int K = KC*32;
  __shared__ short lA[64*32];     // 4 KB
  __shared__ short lB[256*32];    // 16 KB
  const int tid  = threadIdx.x;
  const int lane = tid & 63;
  const int wave = tid >> 6;
  const int m16  = lane & 15;
  const int q    = lane >> 4;
  const int swz  = (m16 >> 1) & 3;
  const int r0   = blockIdx.x * 64;
  const bool first = (blockIdx.y == 0);
  const short* __restrict__ Bt = first ? B1t : B2t;
  short* __restrict__ Cb = first ? C1b : C2b;

  int arow = r0 + (tid >> 2); if (arow >= M) arow = M - 1;
  const int akq = (tid & 3) ^ ((tid >> 3) & 3);
  int bn[4], bkq[4];
  #pragma unroll
  for (int j = 0; j < 4; j++){
    int sj = j*256 + tid;
    bn[j]  = sj >> 2;
    bkq[j] = (sj & 3) ^ ((sj >> 3) & 3);
  }

  f32x4 acc[4][4];
  #pragma unroll
  for (int mi = 0; mi < 4; mi++)
    #pragma unroll
    for (int ni = 0; ni < 4; ni++) acc[mi][ni] = {0.f,0.f,0.f,0.f};

  s16x8 ra = *(const s16x8*)(Ab + (size_t)arow*K + akq*8);
  s16x8 rb[4];
  #pragma unroll
  for (int j = 0; j < 4; j++)
    rb[j] = *(const s16x8*)(Bt + (size_t)bn[j]*K + bkq[j]*8);

  for (int c = 0; c < KC; c++){
    __syncthreads();
    *(s16x8*)(lA + tid*8) = ra;
    #pragma unroll
    for (int j = 0; j < 4; j++)
      *(s16x8*)(lB + (j*256 + tid)*8) = rb[j];
    __syncthreads();

    if (c + 1 < KC){
      int k0 = (c+1)*32;
      ra = *(const s16x8*)(Ab + (size_t)arow*K + k0 + akq*8);
      #pragma unroll
      for (int j = 0; j < 4; j++)
        rb[j] = *(const s16x8*)(Bt + (size_t)bn[j]*K + k0 + bkq[j]*8);
    }

    s16x8 Af[4], Bf[4];
    #pragma unroll
    for (int mi = 0; mi < 4; mi++){
      int slot = (mi*16 + m16)*4 + (q ^ swz);
      Af[mi] = *(const s16x8*)(lA + slot*8);
    }
    #pragma unroll
    for (int ni = 0; ni < 4; ni++){
      int n = wave*64 + ni*16 + m16;
      int slot = n*4 + (q ^ swz);
      Bf[ni] = *(const s16x8*)(lB + slot*8);
    }
    #pragma unroll
    for (int mi = 0; mi < 4; mi++)
      #pragma unroll
      for (int ni = 0; ni < 4; ni++)
        acc[mi][ni] = __builtin_amdgcn_mfma_f32_16x16x32_f16(
            *(h16x8*)&Bf[ni], *(h16x8*)&Af[mi], acc[mi][ni], 0, 0, 0);
  }

  #pragma unroll
  for (int mi = 0; mi < 4; mi++){
    int row = r0 + mi*16 + m16;
    bool ok = (row < M);
    #pragma unroll
    for (int ni = 0; ni < 4; ni++){
      if (ok && Cb){
        size_t o = (size_t)row*256 + wave*64 + ni*16 + q*4;
        short4 u; u.x = f2h(acc[mi][ni][0]); u.y = f2h(acc[mi][ni][1]);
        u.z = f2h(acc[mi][ni][2]); u.w = f2h(acc[mi][ni][3]);
        *(short4*)(Cb + o) = u;
      }
      if (first && asrc){
        // fused svec: head hh = wave*4+ni; lane holds features q*4..q*4+3 of row
        int hh = wave*4 + ni;
        const float* as = asrc + hh*16 + q*4;
        const float* at = atgt + hh*16 + q*4;
        float pss = acc[mi][ni][0]*as[0] + acc[mi][ni][1]*as[1]
                  + acc[mi][ni][2]*as[2] + acc[mi][ni][3]*as[3];
        float pst = acc[mi][ni][0]*at[0] + acc[mi][ni][1]*at[1]
                  + acc[mi][ni][2]*at[2] + acc[mi][ni][3]*at[3];
        pss += __shfl_xor(pss, 16); pss += __shfl_xor(pss, 32);
        pst += __shfl_xor(pst, 16); pst += __shfl_xor(pst, 32);
        if (ok && q == 0){
          s_src[row*16 + hh] = pss;
          s_tgt[row*16 + hh] = pst;
        }
      }
    }
  }

  // ---- per-row-scaled int8 encode (message proj, all layers) ----
  if (first && C8){
    // row max |x| over 256 cols: reduce over k,ni (in-lane), q (shfl), waves (LDS)
    float am[4];
    #pragma unroll
    for (int mi = 0; mi < 4; mi++){
      float a = 0.f;
      #pragma unroll
      for (int ni = 0; ni < 4; ni++)
        #pragma unroll
        for (int k = 0; k < 4; k++)
          a = fmaxf(a, fabsf(acc[mi][ni][k]));
      a = fmaxf(a, __shfl_xor(a, 16));
      a = fmaxf(a, __shfl_xor(a, 32));
      am[mi] = a;
    }
    __syncthreads();                      // all waves done reading lA/lB
    float* rmax = (float*)lA;             // [wave][64 rows] = 1 KB, reuse lA
    if (q == 0){
      #pragma unroll
      for (int mi = 0; mi < 4; mi++) rmax[wave*64 + mi*16 + m16] = am[mi];
    }
    __syncthreads();
    #pragma unroll
    for (int mi = 0; mi < 4; mi++){
      int r = mi*16 + m16;
      int row = r0 + r;
      bool ok = (row < M);
      float s = fmaxf(fmaxf(rmax[r], rmax[64+r]), fmaxf(rmax[128+r], rmax[192+r]));
      float scl = s * (1.f/127.f);
      float inv = (s > 0.f) ? (127.f/s) : 0.f;
      if (ok && wave == 0 && q == 0) pscale[row] = scl;
      if (ok){
        #pragma unroll
        for (int ni = 0; ni < 4; ni++){
          int v0 = __float2int_rn(acc[mi][ni][0]*inv) + 128;
          int v1 = __float2int_rn(acc[mi][ni][1]*inv) + 128;
          int v2 = __float2int_rn(acc[mi][ni][2]*inv) + 128;
          int v3 = __float2int_rn(acc[mi][ni][3]*inv) + 128;
          unsigned pk = (unsigned)(v0 & 255) | ((unsigned)(v1 & 255) << 8)
                      | ((unsigned)(v2 & 255) << 16) | ((unsigned)(v3 & 255) << 24);
          *(unsigned*)(C8 + (size_t)row*256 + wave*64 + ni*16 + q*4) = pk;
        }
      }
    }
  }
}

// ---------------- NH=1 score projections from fp16 proj (wave per node) ----------------
__global__ void k_svec1(const short* __restrict__ Pb,
                        const float* __restrict__ a_src, const float* __restrict__ a_tgt,
                        float* __restrict__ s_src, float* __restrict__ s_tgt, int N){
  int lane = threadIdx.x & 63;
  int node = blockIdx.x*(blockDim.x >> 6) + (threadIdx.x >> 6);
  if (node >= N) return;
  short4 p = ((const short4*)(Pb + (size_t)node*256))[lane];
  const float* as = a_src + lane*4;
  const float* at = a_tgt + lane*4;
  float f0 = h2f(p.x), f1 = h2f(p.y), f2 = h2f(p.z), f3 = h2f(p.w);
  float ss = f0*as[0] + f1*as[1] + f2*as[2] + f3*as[3];
  float st = f0*at[0] + f1*at[1] + f2*at[2] + f3*at[3];
  for (int o = 32; o > 0; o >>= 1){ ss += __shfl_xor(ss, o); st += __shfl_xor(st, o); }
  if (lane == 0){ s_src[node] = ss; s_tgt[node] = st; }
}

// ---------------- single-pass fused attention, NH=16 (int8 proj gather) ----------------
template<int LN>
__global__ __launch_bounds__(256)
void k_attn16(const int* __restrict__ row_start, const int2* __restrict__ es,
              const float* __restrict__ s_src, const float* __restrict__ s_tgt,
              const float* __restrict__ cvec,
              const unsigned char* __restrict__ proj8, const float* __restrict__ pscale,
              const short* __restrict__ skipb,
              const float* __restrict__ bias,
              const float* __restrict__ ln_g, const float* __restrict__ ln_b,
              short* __restrict__ houtb, int N){
  __shared__ __align__(16) float wbuf[4][16][20];   // [wave][head][edge(16)+pad]
  __shared__ __align__(16) int   svbuf[4][16];
  __shared__ __align__(16) float scbuf[4][16];
  const int lane = threadIdx.x & 63;
  const int wave = threadIdx.x >> 6;
  const int node = blockIdx.x*4 + wave;
  if (node >= N) return;
  const int beg = row_start[node], end = row_start[node+1];

  const int h2 = lane >> 2;      // head owning this lane's 4 features (aggregation)
  const int j4 = lane & 15;      // edge slot (score phase)
  const int g  = lane >> 4;      // head-quad (score phase)

  const f32x4 stg = *(const f32x4*)(s_tgt + (size_t)node*16 + g*4);
  const f32x4 cg  = *(const f32x4*)(cvec + g*4);

  float d = 0.f, dws = 0.f;
  float acc0 = 0.f, acc1 = 0.f, acc2 = 0.f, acc3 = 0.f;

  for (int s0 = beg; s0 < end; s0 += 16){
    int cnt = end - s0; if (cnt > 16) cnt = 16;
    // ---- Phase A: scores for 16 edges x 16 heads ----
    int i  = s0 + j4;
    bool valid = (i < end);
    int ic = valid ? i : (end - 1);
    int2 e2 = es[ic];
    int sv = e2.x;
    float tp = __int_as_float(e2.y);
    f32x4 rv = *(const f32x4*)(s_src + (size_t)sv*16 + g*4);
    if (g == 0){ svbuf[wave][j4] = sv; scbuf[wave][j4] = pscale[sv]; }
    #pragma unroll
    for (int k = 0; k < 4; k++){
      float e = rv[k] + stg[k] + tp*cg[k];
      e = (e > 0.f) ? e : 0.2f*e;
      wbuf[wave][g*4 + k][j4] = valid ? __expf(e) : 0.f;
    }
    // ---- Phase B: int8 gather + f32 accumulate (pads carry w=0, sv clamped) ----
    const unsigned* __restrict__ pp = (const unsigned*)proj8 + lane;
    for (int j = 0; j < cnt; j += 4){
      f32x4 w4  = *(const f32x4*)&wbuf[wave][h2][j];
      f32x4 sc4 = *(const f32x4*)&scbuf[wave][j];
      i32x4 sv4 = *(const i32x4*)&svbuf[wave][j];
      unsigned q0 = pp[(size_t)sv4.x*64];
      unsigned q1 = pp[(size_t)sv4.y*64];
      unsigned q2 = pp[(size_t)sv4.z*64];
      unsigned q3 = pp[(size_t)sv4.w*64];
      float ws0 = w4.x*sc4.x, ws1 = w4.y*sc4.y, ws2 = w4.z*sc4.z, ws3 = w4.w*sc4.w;
      d   += (w4.x + w4.y) + (w4.z + w4.w);
      dws += (ws0 + ws1) + (ws2 + ws3);
      acc0 += ws0*(float)(q0 & 255) + ws1*(float)(q1 & 255)
            + ws2*(float)(q2 & 255) + ws3*(float)(q3 & 255);
      acc1 += ws0*(float)((q0 >> 8) & 255) + ws1*(float)((q1 >> 8) & 255)
            + ws2*(float)((q2 >> 8) & 255) + ws3*(float)((q3 >> 8) & 255);
      acc2 += ws0*(float)((q0 >> 16) & 255) + ws1*(float)((q1 >> 16) & 255)
            + ws2*(float)((q2 >> 16) & 255) + ws3*(float)((q3 >> 16) & 255);
      acc3 += ws0*(float)(q0 >> 24) + ws1*(float)(q1 >> 24)
            + ws2*(float)(q2 >> 24) + ws3*(float)(q3 >> 24);
    }
  }
  float inv = 1.f / (d + 1e-16f);
  float c128 = 128.f * dws;

  short4 sk = ((const short4*)(skipb + (size_t)node*256))[lane];
  float acc[4];
  acc[0] = (acc0 - c128)*inv + h2f(sk.x); acc[1] = (acc1 - c128)*inv + h2f(sk.y);
  acc[2] = (acc2 - c128)*inv + h2f(sk.z); acc[3] = (acc3 - c128)*inv + h2f(sk.w);

  #pragma unroll
  for (int j = 0; j < 4; j++){
    float v = acc[j] + bias[lane*4 + j];
    acc[j] = (v > 0.f) ? v : (__expf(v) - 1.f);
  }
  if (LN){
    float s  = acc[0] + acc[1] + acc[2] + acc[3];
    float s2 = acc[0]*acc[0] + acc[1]*acc[1] + acc[2]*acc[2] + acc[3]*acc[3];
    for (int o = 32; o > 0; o >>= 1){ s += __shfl_xor(s, o); s2 += __shfl_xor(s2, o); }
    float mu  = s * (1.f/256.f);
    float var = s2 * (1.f/256.f) - mu*mu;
    float rs  = rsqrtf(var + 1e-5f);
    #pragma unroll
    for (int j = 0; j < 4; j++)
      acc[j] = (acc[j] - mu)*rs*ln_g[lane*4 + j] + ln_b[lane*4 + j];
  }
  short4 ub; ub.x = f2h(acc[0]); ub.y = f2h(acc[1]);
  ub.z = f2h(acc[2]); ub.w = f2h(acc[3]);
  ((short4*)(houtb + (size_t)node*256))[lane] = ub;
}

// NH=1 variant (layer 2): int8 message gather (same scheme as attn16); scores stay
// exact via fp16 Pb in k_svec1. Identity skip, LN, fp16 out.
__global__ __launch_bounds__(256)
void k_attn1(const int* __restrict__ row_start, const int2* __restrict__ es,
             const float* __restrict__ s_src, const float* __restrict__ s_tgt,
             const float* __restrict__ cvec,
             const unsigned char* __restrict__ proj8, const float* __restrict__ pscale,
             const short* __restrict__ skipb,
             const float* __restrict__ bias,
             const float* __restrict__ ln_g, const float* __restrict__ ln_b,
             short* __restrict__ houtb, int N){
  __shared__ __align__(16) float wb1[4][64];
  __shared__ __align__(16) int   sb1[4][64];
  __shared__ __align__(16) float scb1[4][64];
  const int lane = threadIdx.x & 63;
  const int wave = threadIdx.x >> 6;
  const int node = blockIdx.x*4 + wave;
  if (node >= N) return;
  const int beg = row_start[node], end = row_start[node+1];

  const float c0 = cvec[0];
  const float st = s_tgt[node];
  float d = 0.f, dws = 0.f;
  float acc0 = 0.f, acc1 = 0.f, acc2 = 0.f, acc3 = 0.f;

  for (int s0 = beg; s0 < end; s0 += 64){
    int cnt = end - s0; if (cnt > 64) cnt = 64;
    // ---- Phase A: one edge per lane ----
    int i  = s0 + lane;
    bool valid = (i < end);
    int ic = valid ? i : (end - 1);
    int2 e2 = es[ic];
    int sv = e2.x;
    float e = s_src[sv] + st + __int_as_float(e2.y)*c0;
    e = (e > 0.f) ? e : 0.2f*e;
    float w = valid ? __expf(e) : 0.f;
    wb1[wave][lane] = w;
    sb1[wave][lane] = sv;
    scb1[wave][lane] = pscale[sv];
    // ---- Phase B: int8 gather + f32 accumulate (pads carry w=0, sv clamped) ----
    const unsigned* __restrict__ pp = (const unsigned*)proj8 + lane;
    for (int j = 0; j < cnt; j += 4){
      f32x4 w4  = *(const f32x4*)&wb1[wave][j];
      f32x4 sc4 = *(const f32x4*)&scb1[wave][j];
      i32x4 sv4 = *(const i32x4*)&sb1[wave][j];
      unsigned q0 = pp[(size_t)sv4.x*64];
      unsigned q1 = pp[(size_t)sv4.y*64];
      unsigned q2 = pp[(size_t)sv4.z*64];
      unsigned q3 = pp[(size_t)sv4.w*64];
      float ws0 = w4.x*sc4.x, ws1 = w4.y*sc4.y, ws2 = w4.z*sc4.z, ws3 = w4.w*sc4.w;
      d   += (w4.x + w4.y) + (w4.z + w4.w);
      dws += (ws0 + ws1) + (ws2 + ws3);
      acc0 += ws0*(float)(q0 & 255) + ws1*(float)(q1 & 255)
            + ws2*(float)(q2 & 255) + ws3*(float)(q3 & 255);
      acc1 += ws0*(float)((q0 >> 8) & 255) + ws1*(float)((q1 >> 8) & 255)
            + ws2*(float)((q2 >> 8) & 255) + ws3*(float)((q3 >> 8) & 255);
      acc2 += ws0*(float)((q0 >> 16) & 255) + ws1*(float)((q1 >> 16) & 255)
            + ws2*(float)((q2 >> 16) & 255) + ws3*(float)((q3 >> 16) & 255);
      acc3 += ws0*(float)(q0 >> 24) + ws1*(float)(q1 >> 24)
            + ws2*(float)(q2 >> 24) + ws3*(float)(q3 >> 24);
    }
  }
  float inv = 1.f / (d + 1e-16f);
  float c128 = 128.f * dws;

  short4 sk = ((const short4*)(skipb + (size_t)node*256))[lane];
  float acc[4];
  acc[0] = (acc0 - c128)*inv + h2f(sk.x); acc[1] = (acc1 - c128)*inv + h2f(sk.y);
  acc[2] = (acc2 - c128)*inv + h2f(sk.z); acc[3] = (acc3 - c128)*inv + h2f(sk.w);

  #pragma unroll
  for (int j = 0; j < 4; j++){
    float v = acc[j] + bias[lane*4 + j];
    acc[j] = (v > 0.f) ? v : (__expf(v) - 1.f);
  }
  float s  = acc[0] + acc[1] + acc[2] + acc[3];
  float s2 = acc[0]*acc[0] + acc[1]*acc[1] + acc[2]*acc[2] + acc[3]*acc[3];
  for (int o = 32; o > 0; o >>= 1){ s += __shfl_xor(s, o); s2 += __shfl_xor(s2, o); }
  float mu  = s * (1.f/256.f);
  float var = s2 * (1.f/256.f) - mu*mu;
  float rs  = rsqrtf(var + 1e-5f);
  #pragma unroll
  for (int j = 0; j < 4; j++)
    acc[j] = (acc[j] - mu)*rs*ln_g[lane*4 + j] + ln_b[lane*4 + j];
  short4 ub; ub.x = f2h(acc[0]); ub.y = f2h(acc[1]);
  ub.z = f2h(acc[2]); ub.w = f2h(acc[3]);
  ((short4*)(houtb + (size_t)node*256))[lane] = ub;
}

// ---------------- final gather (fp16 h -> fp32 out) ----------------
__global__ void k_gather(const short* hb, const int* x, float* out, int R){
  int r = blockIdx.x, t = threadIdx.x;
  if (r >= R) return;
  out[(size_t)r*256 + t] = h2f(hb[(size_t)x[r]*256 + t]);
}

extern "C" void kernel_launch(void* const* d_in, const int* in_sizes, int n_in,
                              void* d_out, int out_size, void* d_ws, size_t ws_size,
                              hipStream_t stream){
  const int N = in_sizes[0] / 128;   // 50000
  const int E = in_sizes[1] / 2;     // 800000
  const int R = in_sizes[3];         // 8192

  const float* nf    = (const float*)d_in[0];
  const int*   ei    = (const int*)d_in[1];
  const float* eprob = (const float*)d_in[2];
  const int*   xidx  = (const int*)d_in[3];
  const float* W0     = (const float*)d_in[4];
  const float* a_src0 = (const float*)d_in[5];
  const float* a_tgt0 = (const float*)d_in[6];
  const float* Wtp0   = (const float*)d_in[7];
  const float* a_tp0  = (const float*)d_in[8];
  const float* Wskip0 = (const float*)d_in[9];
  const float* b0     = (const float*)d_in[10];
  const float* W1     = (const float*)d_in[11];
  const float* a_src1 = (const float*)d_in[12];
  const float* a_tgt1 = (const float*)d_in[13];
  const float* Wtp1   = (const float*)d_in[14];
  const float* a_tp1  = (const float*)d_in[15];
  const float* Wskip1 = (const float*)d_in[16];
  const float* b1     = (const float*)d_in[17];
  const float* ln1_g  = (const float*)d_in[18];
  const float* ln1_b  = (const float*)d_in[19];
  const float* W2     = (const float*)d_in[20];
  const float* a_src2 = (const float*)d_in[21];
  const float* a_tgt2 = (const float*)d_in[22];
  const float* Wtp2   = (const float*)d_in[23];
  const float* a_tp2  = (const float*)d_in[24];
  const float* b2     = (const float*)d_in[25];
  const float* ln2_g  = (const float*)d_in[26];
  const float* ln2_b  = (const float*)d_in[27];

  // ---- workspace layout (~110 MB) ----
  char* ws = (char*)d_ws;
  size_t off = 0;
  auto alloc = [&](size_t bytes)->char*{
    char* p = ws + off; off = (off + bytes + 255) & ~(size_t)255; return p;
  };
  short* Pb        = (short*)alloc((size_t)N*256*2);   // proj, fp16 (layer 2 scores)
  unsigned char* P8 = (unsigned char*)alloc((size_t)N*256);  // proj, int8 (all layers)
  float* pscale    = (float*)alloc((size_t)N*4);       // per-row int8 scale
  short* hXb       = (short*)alloc((size_t)N*256*2);   // fp16 h: L0 out, then L1 out
  short* Skb       = (short*)alloc((size_t)N*256*2);   // skip GEMM out (L0/L1), then final h
  short* nfb       = (short*)alloc((size_t)N*128*2);   // fp16 node features
  float* s_src     = (float*)alloc((size_t)N*16*4);
  float* s_tgt     = (float*)alloc((size_t)N*16*4);
  float* cvec      = (float*)alloc(256);
  int*   counts    = (int*)alloc((size_t)N*4);
  int*   row_start = (int*)alloc((size_t)(N+1)*4);
  int*   partials  = (int*)alloc(256*4);
  int2*  es        = (int2*)alloc((size_t)E*8);        // packed (src, tp) sorted by tgt
  short* W0t       = (short*)alloc((size_t)128*256*2);
  short* Ws0t      = (short*)alloc((size_t)128*256*2);
  short* W1t       = (short*)alloc((size_t)256*256*2);
  short* Ws1t      = (short*)alloc((size_t)256*256*2);
  short* W2t       = (short*)alloc((size_t)256*256*2);
  (void)ws_size; (void)n_in; (void)out_size;

  const int* src = ei;
  const int* tgt = ei + E;

  // ---- prep: weight transposes + nf convert + cvecs ----
  k_wt<<<(256*128+255)/256, 256, 0, stream>>>(W0,     W0t,  128);
  k_wt<<<(256*128+255)/256, 256, 0, stream>>>(Wskip0, Ws0t, 128);
  k_wt<<<(256*256+255)/256, 256, 0, stream>>>(W1,     W1t,  256);
  k_wt<<<(256*256+255)/256, 256, 0, stream>>>(Wskip1, Ws1t, 256);
  k_wt<<<(256*256+255)/256, 256, 0, stream>>>(W2,     W2t,  256);
  k_cvt<<<((N*128/4)+255)/256, 256, 0, stream>>>(nf, nfb, N*128/4);
  k_cvec<<<1, 256, 0, stream>>>(Wtp0, a_tp0, cvec + 0,  16);
  k_cvec<<<1, 256, 0, stream>>>(Wtp1, a_tp1, cvec + 16, 16);
  k_cvec<<<1, 256, 0, stream>>>(Wtp2, a_tp2, cvec + 32, 1);

  // ---- CSR build ----
  k_zero<<<(N+255)/256, 256, 0, stream>>>(counts, N);
  k_hist<<<(E+255)/256, 256, 0, stream>>>(tgt, counts, E);
  int NB = (N + 1023) / 1024;
  k_scan1<<<NB, 1024, 0, stream>>>(counts, row_start, partials, N);
  k_scan2<<<1, 64, 0, stream>>>(partials, NB);
  k_scan3<<<(N+255)/256, 256, 0, stream>>>(row_start, partials, counts, N, E);
  k_scatter<<<(E+255)/256, 256, 0, stream>>>(src, tgt, eprob, counts, es, E);

  const int gt = (N + 63) / 64;   // GEMM m-tiles
  const int at = (N + 3) / 4;     // attn blocks (4 waves each)

  // ---- Layer 0: GAT(128 -> 16x16 concat), skip = nf @ Wskip0, ELU, no LN ----
  k_gemm_lds<4><<<dim3(gt,2), 256, 0, stream>>>(nfb, W0t, Ws0t, nullptr, Skb, P8, pscale,
                                                a_src0, a_tgt0, s_src, s_tgt, N);
  k_attn16<0><<<at, 256, 0, stream>>>(row_start, es, s_src, s_tgt, cvec + 0,
                                      P8, pscale, Skb, b0, nullptr, nullptr, hXb, N);

  // ---- Layer 1: GAT(256 -> 16x16 concat), skip = h @ Wskip1, ELU, LN ----
  k_gemm_lds<8><<<dim3(gt,2), 256, 0, stream>>>(hXb, W1t, Ws1t, nullptr, Skb, P8, pscale,
                                                a_src1, a_tgt1, s_src, s_tgt, N);
  k_attn16<1><<<at, 256, 0, stream>>>(row_start, es, s_src, s_tgt, cvec + 16,
                                      P8, pscale, Skb, b1, ln1_g, ln1_b, hXb, N);

  // ---- Layer 2: GAT(256 -> 1x256, avg = identity), identity skip, ELU, LN ----
  // GEMM writes fp16 Pb (exact scores via svec1) AND int8 P8 (message gather).
  k_gemm_lds<8><<<dim3(gt,1), 256, 0, stream>>>(hXb, W2t, nullptr, Pb, nullptr,
                                                P8, pscale,
                                                nullptr, nullptr, nullptr, nullptr, N);
  k_svec1<<<at, 256, 0, stream>>>(Pb, a_src2, a_tgt2, s_src, s_tgt, N);
  k_attn1<<<at, 256, 0, stream>>>(row_start, es, s_src, s_tgt, cvec + 32,
                                  P8, pscale, hXb, b2, ln2_g, ln2_b, Skb, N);

  // ---- gather rows into output (fp32) ----
  k_gather<<<R, 256, 0, stream>>>(Skb, xidx, (float*)d_out, R);
}

// Round 8
// 470.741 us; speedup vs baseline: 1.1819x; 1.0673x over previous
//
#include <hip/hip_runtime.h>
#include <hip/hip_fp16.h>
#include <math.h>

typedef __attribute__((ext_vector_type(8))) short    s16x8;   // 8 fp16 (4 VGPRs)
typedef __attribute__((ext_vector_type(8))) _Float16 h16x8;   // MFMA f16 operand
typedef __attribute__((ext_vector_type(4))) float    f32x4;   // MFMA accumulator
typedef __attribute__((ext_vector_type(4))) int      i32x4;

__device__ __forceinline__ short f2h(float x){ return __half_as_short(__float2half(x)); }
__device__ __forceinline__ float h2f(short s){ return __half2float(__short_as_half(s)); }

// ---------------- fp32 -> fp16 convert (n % 4 == 0) ----------------
__global__ void k_cvt(const float* __restrict__ in, short* __restrict__ outb, int n4){
  int i = blockIdx.x*blockDim.x + threadIdx.x;
  if (i >= n4) return;
  float4 v = ((const float4*)in)[i];
  short4 u; u.x = f2h(v.x); u.y = f2h(v.y); u.z = f2h(v.z); u.w = f2h(v.w);
  ((short4*)outb)[i] = u;
}

// ---------------- fused prep: 5 weight transposes + 3 cvec reductions ----------------
// blocks 0..1023: transpose+convert (262144 elems total, partitioned by range).
// blocks 1024..1026: cvec[layer] reduction.
__global__ void k_prep(const float* W0, const float* Ws0, const float* W1,
                       const float* Ws1, const float* W2,
                       short* W0t, short* Ws0t, short* W1t, short* Ws1t, short* W2t,
                       const float* Wtp0, const float* a_tp0,
                       const float* Wtp1, const float* a_tp1,
                       const float* Wtp2, const float* a_tp2, float* cvec){
  __shared__ float buf[256];
  int b = blockIdx.x;
  if (b < 1024){
    int idx = b*256 + threadIdx.x;           // 0..262143
    const float* W; short* Wt; int K; int base;
    if (idx < 32768)      { W=W0;  Wt=W0t;  K=128; base=0; }
    else if (idx < 65536) { W=Ws0; Wt=Ws0t; K=128; base=32768; }
    else if (idx < 131072){ W=W1;  Wt=W1t;  K=256; base=65536; }
    else if (idx < 196608){ W=Ws1; Wt=Ws1t; K=256; base=131072; }
    else                  { W=W2;  Wt=W2t;  K=256; base=196608; }
    int i = idx - base;
    int n = i / K, k = i - n*K;
    Wt[i] = f2h(W[(size_t)k*256 + n]);
  } else {
    int layer = b - 1024;
    const float* Wtp = layer==0 ? Wtp0 : (layer==1 ? Wtp1 : Wtp2);
    const float* atp = layer==0 ? a_tp0 : (layer==1 ? a_tp1 : a_tp2);
    float* c = cvec + (layer==0 ? 0 : (layer==1 ? 16 : 32));
    int NH = (layer==2) ? 1 : 16;
    int t = threadIdx.x;
    buf[t] = Wtp[t] * atp[t];
    __syncthreads();
    int F = 256 / NH;
    if (t < NH){
      float s = 0.f;
      for (int f = 0; f < F; f++) s += buf[t*F + f];
      c[t] = s;
    }
  }
}

// ---------------- CSR build (sort edges by target) ----------------
__global__ void k_hist(const int* tgt, int* counts, int E){
  int i = blockIdx.x*blockDim.x + threadIdx.x;
  if (i < E) atomicAdd(&counts[tgt[i]], 1);
}
__global__ void k_scan1(const int* counts, int* row_excl, int* partials, int N){
  __shared__ int buf[1024];
  int t = threadIdx.x; int i = blockIdx.x*1024 + t;
  int v = (i < N) ? counts[i] : 0;
  buf[t] = v; __syncthreads();
  for (int o = 1; o < 1024; o <<= 1){
    int x = (t >= o) ? buf[t-o] : 0;
    __syncthreads();
    buf[t] += x;
    __syncthreads();
  }
  if (i < N) row_excl[i] = buf[t] - v;
  if (t == 1023) partials[blockIdx.x] = buf[1023];
}
__global__ void k_scan2(int* partials, int NB){
  if (threadIdx.x == 0 && blockIdx.x == 0){
    int s = 0;
    for (int b = 0; b < NB; b++){ int v = partials[b]; partials[b] = s; s += v; }
  }
}
__global__ void k_scan3(int* row_start, const int* partials, int* cursor, int N, int E){
  int i = blockIdx.x*blockDim.x + threadIdx.x;
  if (i < N){
    int v = row_start[i] + partials[i >> 10];
    row_start[i] = v; cursor[i] = v;
  }
  if (i == 0) row_start[N] = E;
}
// pack (src, transition_prob) as int2 for one 8B load per edge in attention
__global__ void k_scatter(const int* src, const int* tgt, const float* eprob,
                          int* cursor, int2* es, int E){
  int i = blockIdx.x*blockDim.x + threadIdx.x;
  if (i >= E) return;
  int tg = tgt[i];
  int p = atomicAdd(&cursor[tg], 1);
  int2 v; v.x = src[i]; v.y = __float_as_int(eprob[i]);
  es[p] = v;
}

// ---------------- LDS-staged MFMA GEMM (fp16 in, fp16/int8 out) ----------------
// y=0: proj -> int8 C8+pscale (if non-null), optional fp16 C1b, fused NH=16 svec
//      (asrc/atgt) or fused NH=1 svec (asrc1/atgt1, full-row dot via LDS reduce).
// y=1: skip -> fp16 C2b.
template<int KC>   // K/32 chunks: 4 (K=128) or 8 (K=256)
__global__ __launch_bounds__(256)
void k_gemm_lds(const short* __restrict__ Ab,
                const short* __restrict__ B1t, const short* __restrict__ B2t,
                short* __restrict__ C1b, short* __restrict__ C2b,
                unsigned char* __restrict__ C8, float* __restrict__ pscale,
                const float* __restrict__ asrc, const float* __restrict__ atgt,
                const float* __restrict__ asrc1, const float* __restrict__ atgt1,
                float* __restrict__ s_src, float* __restrict__ s_tgt, int M){
  const int K = KC*32;
  __shared__ short lA[64*32];     // 4 KB
  __shared__ short lB[256*32];    // 16 KB
  const int tid  = threadIdx.x;
  const int lane = tid & 63;
  const int wave = tid >> 6;
  const int m16  = lane & 15;
  const int q    = lane >> 4;
  const int swz  = (m16 >> 1) & 3;
  const int r0   = blockIdx.x * 64;
  const bool first = (blockIdx.y == 0);
  const short* __restrict__ Bt = first ? B1t : B2t;
  short* __restrict__ Cb = first ? C1b : C2b;

  int arow = r0 + (tid >> 2); if (arow >= M) arow = M - 1;
  const int akq = (tid & 3) ^ ((tid >> 3) & 3);
  int bn[4], bkq[4];
  #pragma unroll
  for (int j = 0; j < 4; j++){
    int sj = j*256 + tid;
    bn[j]  = sj >> 2;
    bkq[j] = (sj & 3) ^ ((sj >> 3) & 3);
  }

  f32x4 acc[4][4];
  #pragma unroll
  for (int mi = 0; mi < 4; mi++)
    #pragma unroll
    for (int ni = 0; ni < 4; ni++) acc[mi][ni] = {0.f,0.f,0.f,0.f};

  s16x8 ra = *(const s16x8*)(Ab + (size_t)arow*K + akq*8);
  s16x8 rb[4];
  #pragma unroll
  for (int j = 0; j < 4; j++)
    rb[j] = *(const s16x8*)(Bt + (size_t)bn[j]*K + bkq[j]*8);

  for (int c = 0; c < KC; c++){
    __syncthreads();
    *(s16x8*)(lA + tid*8) = ra;
    #pragma unroll
    for (int j = 0; j < 4; j++)
      *(s16x8*)(lB + (j*256 + tid)*8) = rb[j];
    __syncthreads();

    if (c + 1 < KC){
      int k0 = (c+1)*32;
      ra = *(const s16x8*)(Ab + (size_t)arow*K + k0 + akq*8);
      #pragma unroll
      for (int j = 0; j < 4; j++)
        rb[j] = *(const s16x8*)(Bt + (size_t)bn[j]*K + k0 + bkq[j]*8);
    }

    s16x8 Af[4], Bf[4];
    #pragma unroll
    for (int mi = 0; mi < 4; mi++){
      int slot = (mi*16 + m16)*4 + (q ^ swz);
      Af[mi] = *(const s16x8*)(lA + slot*8);
    }
    #pragma unroll
    for (int ni = 0; ni < 4; ni++){
      int n = wave*64 + ni*16 + m16;
      int slot = n*4 + (q ^ swz);
      Bf[ni] = *(const s16x8*)(lB + slot*8);
    }
    #pragma unroll
    for (int mi = 0; mi < 4; mi++)
      #pragma unroll
      for (int ni = 0; ni < 4; ni++)
        acc[mi][ni] = __builtin_amdgcn_mfma_f32_16x16x32_f16(
            *(h16x8*)&Bf[ni], *(h16x8*)&Af[mi], acc[mi][ni], 0, 0, 0);
  }

  #pragma unroll
  for (int mi = 0; mi < 4; mi++){
    int row = r0 + mi*16 + m16;
    bool ok = (row < M);
    #pragma unroll
    for (int ni = 0; ni < 4; ni++){
      if (ok && Cb){
        size_t o = (size_t)row*256 + wave*64 + ni*16 + q*4;
        short4 u; u.x = f2h(acc[mi][ni][0]); u.y = f2h(acc[mi][ni][1]);
        u.z = f2h(acc[mi][ni][2]); u.w = f2h(acc[mi][ni][3]);
        *(short4*)(Cb + o) = u;
      }
      if (first && asrc){
        // fused NH=16 svec: head hh = wave*4+ni; lane holds features q*4..q*4+3
        int hh = wave*4 + ni;
        const float* as = asrc + hh*16 + q*4;
        const float* at = atgt + hh*16 + q*4;
        float pss = acc[mi][ni][0]*as[0] + acc[mi][ni][1]*as[1]
                  + acc[mi][ni][2]*as[2] + acc[mi][ni][3]*as[3];
        float pst = acc[mi][ni][0]*at[0] + acc[mi][ni][1]*at[1]
                  + acc[mi][ni][2]*at[2] + acc[mi][ni][3]*at[3];
        pss += __shfl_xor(pss, 16); pss += __shfl_xor(pss, 32);
        pst += __shfl_xor(pst, 16); pst += __shfl_xor(pst, 32);
        if (ok && q == 0){
          s_src[row*16 + hh] = pss;
          s_tgt[row*16 + hh] = pst;
        }
      }
    }
  }

  // ---- fused NH=1 svec (layer 2): full 256-col dot per row, cross-wave LDS reduce ----
  if (first && asrc1){
    float pss[4], pst[4];
    #pragma unroll
    for (int mi = 0; mi < 4; mi++){
      float ss = 0.f, st = 0.f;
      #pragma unroll
      for (int ni = 0; ni < 4; ni++){
        const float* as = asrc1 + wave*64 + ni*16 + q*4;
        const float* at = atgt1 + wave*64 + ni*16 + q*4;
        #pragma unroll
        for (int k = 0; k < 4; k++){
          ss += acc[mi][ni][k]*as[k];
          st += acc[mi][ni][k]*at[k];
        }
      }
      ss += __shfl_xor(ss, 16); ss += __shfl_xor(ss, 32);
      st += __shfl_xor(st, 16); st += __shfl_xor(st, 32);
      pss[mi] = ss; pst[mi] = st;
    }
    __syncthreads();                       // main-loop lB reads done
    float* sred = (float*)lB;              // [2][4 waves][64 rows] = 2 KB
    if (q == 0){
      #pragma unroll
      for (int mi = 0; mi < 4; mi++){
        int r = mi*16 + m16;
        sred[wave*64 + r]       = pss[mi];
        sred[256 + wave*64 + r] = pst[mi];
      }
    }
    __syncthreads();
    if (tid < 64){
      int row = r0 + tid;
      if (row < M){
        float ss = sred[tid] + sred[64+tid] + sred[128+tid] + sred[192+tid];
        float st = sred[256+tid] + sred[320+tid] + sred[384+tid] + sred[448+tid];
        s_src[row] = ss;
        s_tgt[row] = st;
      }
    }
  }

  // ---- per-row-scaled int8 encode (message proj, all layers) ----
  if (first && C8){
    // row max |x| over 256 cols: reduce over k,ni (in-lane), q (shfl), waves (LDS)
    float am[4];
    #pragma unroll
    for (int mi = 0; mi < 4; mi++){
      float a = 0.f;
      #pragma unroll
      for (int ni = 0; ni < 4; ni++)
        #pragma unroll
        for (int k = 0; k < 4; k++)
          a = fmaxf(a, fabsf(acc[mi][ni][k]));
      a = fmaxf(a, __shfl_xor(a, 16));
      a = fmaxf(a, __shfl_xor(a, 32));
      am[mi] = a;
    }
    __syncthreads();                      // all waves done with prior LDS use
    float* rmax = (float*)lA;             // [wave][64 rows] = 1 KB, reuse lA
    if (q == 0){
      #pragma unroll
      for (int mi = 0; mi < 4; mi++) rmax[wave*64 + mi*16 + m16] = am[mi];
    }
    __syncthreads();
    #pragma unroll
    for (int mi = 0; mi < 4; mi++){
      int r = mi*16 + m16;
      int row = r0 + r;
      bool ok = (row < M);
      float s = fmaxf(fmaxf(rmax[r], rmax[64+r]), fmaxf(rmax[128+r], rmax[192+r]));
      float scl = s * (1.f/127.f);
      float inv = (s > 0.f) ? (127.f/s) : 0.f;
      if (ok && wave == 0 && q == 0) pscale[row] = scl;
      if (ok){
        #pragma unroll
        for (int ni = 0; ni < 4; ni++){
          int v0 = __float2int_rn(acc[mi][ni][0]*inv) + 128;
          int v1 = __float2int_rn(acc[mi][ni][1]*inv) + 128;
          int v2 = __float2int_rn(acc[mi][ni][2]*inv) + 128;
          int v3 = __float2int_rn(acc[mi][ni][3]*inv) + 128;
          unsigned pk = (unsigned)(v0 & 255) | ((unsigned)(v1 & 255) << 8)
                      | ((unsigned)(v2 & 255) << 16) | ((unsigned)(v3 & 255) << 24);
          *(unsigned*)(C8 + (size_t)row*256 + wave*64 + ni*16 + q*4) = pk;
        }
      }
    }
  }
}

// ---------------- single-pass fused attention, NH=16 (int8 proj gather) ----------------
template<int LN>
__global__ __launch_bounds__(256)
void k_attn16(const int* __restrict__ row_start, const int2* __restrict__ es,
              const float* __restrict__ s_src, const float* __restrict__ s_tgt,
              const float* __restrict__ cvec,
              const unsigned char* __restrict__ proj8, const float* __restrict__ pscale,
              const short* __restrict__ skipb,
              const float* __restrict__ bias,
              const float* __restrict__ ln_g, const float* __restrict__ ln_b,
              short* __restrict__ houtb, int N){
  __shared__ __align__(16) float wbuf[4][16][20];   // [wave][head][edge(16)+pad]
  __shared__ __align__(16) int   svbuf[4][16];
  __shared__ __align__(16) float scbuf[4][16];
  const int lane = threadIdx.x & 63;
  const int wave = threadIdx.x >> 6;
  const int node = blockIdx.x*4 + wave;
  if (node >= N) return;
  const int beg = row_start[node], end = row_start[node+1];

  const int h2 = lane >> 2;      // head owning this lane's 4 features (aggregation)
  const int j4 = lane & 15;      // edge slot (score phase)
  const int g  = lane >> 4;      // head-quad (score phase)

  const f32x4 stg = *(const f32x4*)(s_tgt + (size_t)node*16 + g*4);
  const f32x4 cg  = *(const f32x4*)(cvec + g*4);

  float d = 0.f, dws = 0.f;
  float acc0 = 0.f, acc1 = 0.f, acc2 = 0.f, acc3 = 0.f;

  for (int s0 = beg; s0 < end; s0 += 16){
    int cnt = end - s0; if (cnt > 16) cnt = 16;
    // ---- Phase A: scores for 16 edges x 16 heads ----
    int i  = s0 + j4;
    bool valid = (i < end);
    int ic = valid ? i : (end - 1);
    int2 e2 = es[ic];
    int sv = e2.x;
    float tp = __int_as_float(e2.y);
    f32x4 rv = *(const f32x4*)(s_src + (size_t)sv*16 + g*4);
    if (g == 0){ svbuf[wave][j4] = sv; scbuf[wave][j4] = pscale[sv]; }
    #pragma unroll
    for (int k = 0; k < 4; k++){
      float e = rv[k] + stg[k] + tp*cg[k];
      e = (e > 0.f) ? e : 0.2f*e;
      wbuf[wave][g*4 + k][j4] = valid ? __expf(e) : 0.f;
    }
    // ---- Phase B: int8 gather + f32 accumulate (pads carry w=0, sv clamped) ----
    const unsigned* __restrict__ pp = (const unsigned*)proj8 + lane;
    for (int j = 0; j < cnt; j += 4){
      f32x4 w4  = *(const f32x4*)&wbuf[wave][h2][j];
      f32x4 sc4 = *(const f32x4*)&scbuf[wave][j];
      i32x4 sv4 = *(const i32x4*)&svbuf[wave][j];
      unsigned q0 = pp[(size_t)sv4.x*64];
      unsigned q1 = pp[(size_t)sv4.y*64];
      unsigned q2 = pp[(size_t)sv4.z*64];
      unsigned q3 = pp[(size_t)sv4.w*64];
      float ws0 = w4.x*sc4.x, ws1 = w4.y*sc4.y, ws2 = w4.z*sc4.z, ws3 = w4.w*sc4.w;
      d   += (w4.x + w4.y) + (w4.z + w4.w);
      dws += (ws0 + ws1) + (ws2 + ws3);
      acc0 += ws0*(float)(q0 & 255) + ws1*(float)(q1 & 255)
            + ws2*(float)(q2 & 255) + ws3*(float)(q3 & 255);
      acc1 += ws0*(float)((q0 >> 8) & 255) + ws1*(float)((q1 >> 8) & 255)
            + ws2*(float)((q2 >> 8) & 255) + ws3*(float)((q3 >> 8) & 255);
      acc2 += ws0*(float)((q0 >> 16) & 255) + ws1*(float)((q1 >> 16) & 255)
            + ws2*(float)((q2 >> 16) & 255) + ws3*(float)((q3 >> 16) & 255);
      acc3 += ws0*(float)(q0 >> 24) + ws1*(float)(q1 >> 24)
            + ws2*(float)(q2 >> 24) + ws3*(float)(q3 >> 24);
    }
  }
  float inv = 1.f / (d + 1e-16f);
  float c128 = 128.f * dws;

  short4 sk = ((const short4*)(skipb + (size_t)node*256))[lane];
  float acc[4];
  acc[0] = (acc0 - c128)*inv + h2f(sk.x); acc[1] = (acc1 - c128)*inv + h2f(sk.y);
  acc[2] = (acc2 - c128)*inv + h2f(sk.z); acc[3] = (acc3 - c128)*inv + h2f(sk.w);

  #pragma unroll
  for (int j = 0; j < 4; j++){
    float v = acc[j] + bias[lane*4 + j];
    acc[j] = (v > 0.f) ? v : (__expf(v) - 1.f);
  }
  if (LN){
    float s  = acc[0] + acc[1] + acc[2] + acc[3];
    float s2 = acc[0]*acc[0] + acc[1]*acc[1] + acc[2]*acc[2] + acc[3]*acc[3];
    for (int o = 32; o > 0; o >>= 1){ s += __shfl_xor(s, o); s2 += __shfl_xor(s2, o); }
    float mu  = s * (1.f/256.f);
    float var = s2 * (1.f/256.f) - mu*mu;
    float rs  = rsqrtf(var + 1e-5f);
    #pragma unroll
    for (int j = 0; j < 4; j++)
      acc[j] = (acc[j] - mu)*rs*ln_g[lane*4 + j] + ln_b[lane*4 + j];
  }
  short4 ub; ub.x = f2h(acc[0]); ub.y = f2h(acc[1]);
  ub.z = f2h(acc[2]); ub.w = f2h(acc[3]);
  ((short4*)(houtb + (size_t)node*256))[lane] = ub;
}

// NH=1 variant (layer 2): int8 message gather; scores from fused GEMM-epilogue svec.
// Identity skip, LN, fp16 out.
__global__ __launch_bounds__(256)
void k_attn1(const int* __restrict__ row_start, const int2* __restrict__ es,
             const float* __restrict__ s_src, const float* __restrict__ s_tgt,
             const float* __restrict__ cvec,
             const unsigned char* __restrict__ proj8, const float* __restrict__ pscale,
             const short* __restrict__ skipb,
             const float* __restrict__ bias,
             const float* __restrict__ ln_g, const float* __restrict__ ln_b,
             short* __restrict__ houtb, int N){
  __shared__ __align__(16) float wb1[4][64];
  __shared__ __align__(16) int   sb1[4][64];
  __shared__ __align__(16) float scb1[4][64];
  const int lane = threadIdx.x & 63;
  const int wave = threadIdx.x >> 6;
  const int node = blockIdx.x*4 + wave;
  if (node >= N) return;
  const int beg = row_start[node], end = row_start[node+1];

  const float c0 = cvec[0];
  const float st = s_tgt[node];
  float d = 0.f, dws = 0.f;
  float acc0 = 0.f, acc1 = 0.f, acc2 = 0.f, acc3 = 0.f;

  for (int s0 = beg; s0 < end; s0 += 64){
    int cnt = end - s0; if (cnt > 64) cnt = 64;
    // ---- Phase A: one edge per lane ----
    int i  = s0 + lane;
    bool valid = (i < end);
    int ic = valid ? i : (end - 1);
    int2 e2 = es[ic];
    int sv = e2.x;
    float e = s_src[sv] + st + __int_as_float(e2.y)*c0;
    e = (e > 0.f) ? e : 0.2f*e;
    float w = valid ? __expf(e) : 0.f;
    wb1[wave][lane] = w;
    sb1[wave][lane] = sv;
    scb1[wave][lane] = pscale[sv];
    // ---- Phase B: int8 gather + f32 accumulate (pads carry w=0, sv clamped) ----
    const unsigned* __restrict__ pp = (const unsigned*)proj8 + lane;
    for (int j = 0; j < cnt; j += 4){
      f32x4 w4  = *(const f32x4*)&wb1[wave][j];
      f32x4 sc4 = *(const f32x4*)&scb1[wave][j];
      i32x4 sv4 = *(const i32x4*)&sb1[wave][j];
      unsigned q0 = pp[(size_t)sv4.x*64];
      unsigned q1 = pp[(size_t)sv4.y*64];
      unsigned q2 = pp[(size_t)sv4.z*64];
      unsigned q3 = pp[(size_t)sv4.w*64];
      float ws0 = w4.x*sc4.x, ws1 = w4.y*sc4.y, ws2 = w4.z*sc4.z, ws3 = w4.w*sc4.w;
      d   += (w4.x + w4.y) + (w4.z + w4.w);
      dws += (ws0 + ws1) + (ws2 + ws3);
      acc0 += ws0*(float)(q0 & 255) + ws1*(float)(q1 & 255)
            + ws2*(float)(q2 & 255) + ws3*(float)(q3 & 255);
      acc1 += ws0*(float)((q0 >> 8) & 255) + ws1*(float)((q1 >> 8) & 255)
            + ws2*(float)((q2 >> 8) & 255) + ws3*(float)((q3 >> 8) & 255);
      acc2 += ws0*(float)((q0 >> 16) & 255) + ws1*(float)((q1 >> 16) & 255)
            + ws2*(float)((q2 >> 16) & 255) + ws3*(float)((q3 >> 16) & 255);
      acc3 += ws0*(float)(q0 >> 24) + ws1*(float)(q1 >> 24)
            + ws2*(float)(q2 >> 24) + ws3*(float)(q3 >> 24);
    }
  }
  float inv = 1.f / (d + 1e-16f);
  float c128 = 128.f * dws;

  short4 sk = ((const short4*)(skipb + (size_t)node*256))[lane];
  float acc[4];
  acc[0] = (acc0 - c128)*inv + h2f(sk.x); acc[1] = (acc1 - c128)*inv + h2f(sk.y);
  acc[2] = (acc2 - c128)*inv + h2f(sk.z); acc[3] = (acc3 - c128)*inv + h2f(sk.w);

  #pragma unroll
  for (int j = 0; j < 4; j++){
    float v = acc[j] + bias[lane*4 + j];
    acc[j] = (v > 0.f) ? v : (__expf(v) - 1.f);
  }
  float s  = acc[0] + acc[1] + acc[2] + acc[3];
  float s2 = acc[0]*acc[0] + acc[1]*acc[1] + acc[2]*acc[2] + acc[3]*acc[3];
  for (int o = 32; o > 0; o >>= 1){ s += __shfl_xor(s, o); s2 += __shfl_xor(s2, o); }
  float mu  = s * (1.f/256.f);
  float var = s2 * (1.f/256.f) - mu*mu;
  float rs  = rsqrtf(var + 1e-5f);
  #pragma unroll
  for (int j = 0; j < 4; j++)
    acc[j] = (acc[j] - mu)*rs*ln_g[lane*4 + j] + ln_b[lane*4 + j];
  short4 ub; ub.x = f2h(acc[0]); ub.y = f2h(acc[1]);
  ub.z = f2h(acc[2]); ub.w = f2h(acc[3]);
  ((short4*)(houtb + (size_t)node*256))[lane] = ub;
}

// ---------------- final gather (fp16 h -> fp32 out) ----------------
__global__ void k_gather(const short* hb, const int* x, float* out, int R){
  int r = blockIdx.x, t = threadIdx.x;
  if (r >= R) return;
  out[(size_t)r*256 + t] = h2f(hb[(size_t)x[r]*256 + t]);
}

extern "C" void kernel_launch(void* const* d_in, const int* in_sizes, int n_in,
                              void* d_out, int out_size, void* d_ws, size_t ws_size,
                              hipStream_t stream){
  const int N = in_sizes[0] / 128;   // 50000
  const int E = in_sizes[1] / 2;     // 800000
  const int R = in_sizes[3];         // 8192

  const float* nf    = (const float*)d_in[0];
  const int*   ei    = (const int*)d_in[1];
  const float* eprob = (const float*)d_in[2];
  const int*   xidx  = (const int*)d_in[3];
  const float* W0     = (const float*)d_in[4];
  const float* a_src0 = (const float*)d_in[5];
  const float* a_tgt0 = (const float*)d_in[6];
  const float* Wtp0   = (const float*)d_in[7];
  const float* a_tp0  = (const float*)d_in[8];
  const float* Wskip0 = (const float*)d_in[9];
  const float* b0     = (const float*)d_in[10];
  const float* W1     = (const float*)d_in[11];
  const float* a_src1 = (const float*)d_in[12];
  const float* a_tgt1 = (const float*)d_in[13];
  const float* Wtp1   = (const float*)d_in[14];
  const float* a_tp1  = (const float*)d_in[15];
  const float* Wskip1 = (const float*)d_in[16];
  const float* b1     = (const float*)d_in[17];
  const float* ln1_g  = (const float*)d_in[18];
  const float* ln1_b  = (const float*)d_in[19];
  const float* W2     = (const float*)d_in[20];
  const float* a_src2 = (const float*)d_in[21];
  const float* a_tgt2 = (const float*)d_in[22];
  const float* Wtp2   = (const float*)d_in[23];
  const float* a_tp2  = (const float*)d_in[24];
  const float* b2     = (const float*)d_in[25];
  const float* ln2_g  = (const float*)d_in[26];
  const float* ln2_b  = (const float*)d_in[27];

  // ---- workspace layout (~85 MB) ----
  char* ws = (char*)d_ws;
  size_t off = 0;
  auto alloc = [&](size_t bytes)->char*{
    char* p = ws + off; off = (off + bytes + 255) & ~(size_t)255; return p;
  };
  unsigned char* P8 = (unsigned char*)alloc((size_t)N*256);  // proj, int8 (all layers)
  float* pscale    = (float*)alloc((size_t)N*4);       // per-row int8 scale
  short* hXb       = (short*)alloc((size_t)N*256*2);   // fp16 h: L0 out, then L1 out
  short* Skb       = (short*)alloc((size_t)N*256*2);   // skip GEMM out (L0/L1), then final h
  short* nfb       = (short*)alloc((size_t)N*128*2);   // fp16 node features
  float* s_src     = (float*)alloc((size_t)N*16*4);
  float* s_tgt     = (float*)alloc((size_t)N*16*4);
  float* cvec      = (float*)alloc(256);
  int*   counts    = (int*)alloc((size_t)N*4);
  int*   row_start = (int*)alloc((size_t)(N+1)*4);
  int*   partials  = (int*)alloc(256*4);
  int2*  es        = (int2*)alloc((size_t)E*8);        // packed (src, tp) sorted by tgt
  short* W0t       = (short*)alloc((size_t)128*256*2);
  short* Ws0t      = (short*)alloc((size_t)128*256*2);
  short* W1t       = (short*)alloc((size_t)256*256*2);
  short* Ws1t      = (short*)alloc((size_t)256*256*2);
  short* W2t       = (short*)alloc((size_t)256*256*2);
  (void)ws_size; (void)n_in; (void)out_size;

  const int* src = ei;
  const int* tgt = ei + E;

  // ---- prep: fused transposes+cvecs, nf convert, counts clear ----
  k_prep<<<1027, 256, 0, stream>>>(W0, Wskip0, W1, Wskip1, W2,
                                   W0t, Ws0t, W1t, Ws1t, W2t,
                                   Wtp0, a_tp0, Wtp1, a_tp1, Wtp2, a_tp2, cvec);
  k_cvt<<<((N*128/4)+255)/256, 256, 0, stream>>>(nf, nfb, N*128/4);
  hipMemsetAsync(counts, 0, (size_t)N*4, stream);

  // ---- CSR build ----
  k_hist<<<(E+255)/256, 256, 0, stream>>>(tgt, counts, E);
  int NB = (N + 1023) / 1024;
  k_scan1<<<NB, 1024, 0, stream>>>(counts, row_start, partials, N);
  k_scan2<<<1, 64, 0, stream>>>(partials, NB);
  k_scan3<<<(N+255)/256, 256, 0, stream>>>(row_start, partials, counts, N, E);
  k_scatter<<<(E+255)/256, 256, 0, stream>>>(src, tgt, eprob, counts, es, E);

  const int gt = (N + 63) / 64;   // GEMM m-tiles
  const int at = (N + 3) / 4;     // attn blocks (4 waves each)

  // ---- Layer 0: GAT(128 -> 16x16 concat), skip = nf @ Wskip0, ELU, no LN ----
  k_gemm_lds<4><<<dim3(gt,2), 256, 0, stream>>>(nfb, W0t, Ws0t, nullptr, Skb, P8, pscale,
                                                a_src0, a_tgt0, nullptr, nullptr,
                                                s_src, s_tgt, N);
  k_attn16<0><<<at, 256, 0, stream>>>(row_start, es, s_src, s_tgt, cvec + 0,
                                      P8, pscale, Skb, b0, nullptr, nullptr, hXb, N);

  // ---- Layer 1: GAT(256 -> 16x16 concat), skip = h @ Wskip1, ELU, LN ----
  k_gemm_lds<8><<<dim3(gt,2), 256, 0, stream>>>(hXb, W1t, Ws1t, nullptr, Skb, P8, pscale,
                                                a_src1, a_tgt1, nullptr, nullptr,
                                                s_src, s_tgt, N);
  k_attn16<1><<<at, 256, 0, stream>>>(row_start, es, s_src, s_tgt, cvec + 16,
                                      P8, pscale, Skb, b1, ln1_g, ln1_b, hXb, N);

  // ---- Layer 2: GAT(256 -> 1x256, avg = identity), identity skip, ELU, LN ----
  // GEMM emits int8 P8 + pscale and fused NH=1 svec (s_src/s_tgt from exact f32).
  k_gemm_lds<8><<<dim3(gt,1), 256, 0, stream>>>(hXb, W2t, nullptr, nullptr, nullptr,
                                                P8, pscale,
                                                nullptr, nullptr, a_src2, a_tgt2,
                                                s_src, s_tgt, N);
  k_attn1<<<at, 256, 0, stream>>>(row_start, es, s_src, s_tgt, cvec + 32,
                                  P8, pscale, hXb, b2, ln2_g, ln2_b, Skb, N);

  // ---- gather rows into output (fp32) ----
  k_gather<<<R, 256, 0, stream>>>(Skb, xidx, (float*)d_out, R);
}

// Round 9
// 443.788 us; speedup vs baseline: 1.2537x; 1.0607x over previous
//
#include <hip/hip_runtime.h>
#include <hip/hip_fp16.h>
#include <math.h>

typedef __attribute__((ext_vector_type(8))) short    s16x8;   // 8 fp16 (4 VGPRs)
typedef __attribute__((ext_vector_type(8))) _Float16 h16x8;   // MFMA f16 operand
typedef __attribute__((ext_vector_type(4))) float    f32x4;   // MFMA accumulator
typedef __attribute__((ext_vector_type(4))) int      i32x4;

__device__ __forceinline__ short f2h(float x){ return __half_as_short(__float2half(x)); }
__device__ __forceinline__ float h2f(short s){ return __half2float(__short_as_half(s)); }

// ---------------- fused prep: 5 weight transposes + 3 cvec reductions + counts zero ----
// blocks 0..1023: transpose+convert (262144 elems, partitioned by range).
// blocks 1024..1026: cvec[layer] reduction.
// blocks 1027.. : zero counts[N].
__global__ void k_prep(const float* W0, const float* Ws0, const float* W1,
                       const float* Ws1, const float* W2,
                       short* W0t, short* Ws0t, short* W1t, short* Ws1t, short* W2t,
                       const float* Wtp0, const float* a_tp0,
                       const float* Wtp1, const float* a_tp1,
                       const float* Wtp2, const float* a_tp2, float* cvec,
                       int* counts, int N){
  __shared__ float buf[256];
  int b = blockIdx.x;
  if (b < 1024){
    int idx = b*256 + threadIdx.x;           // 0..262143
    const float* W; short* Wt; int K; int base;
    if (idx < 32768)      { W=W0;  Wt=W0t;  K=128; base=0; }
    else if (idx < 65536) { W=Ws0; Wt=Ws0t; K=128; base=32768; }
    else if (idx < 131072){ W=W1;  Wt=W1t;  K=256; base=65536; }
    else if (idx < 196608){ W=Ws1; Wt=Ws1t; K=256; base=131072; }
    else                  { W=W2;  Wt=W2t;  K=256; base=196608; }
    int i = idx - base;
    int n = i / K, k = i - n*K;
    Wt[i] = f2h(W[(size_t)k*256 + n]);
  } else if (b < 1027){
    int layer = b - 1024;
    const float* Wtp = layer==0 ? Wtp0 : (layer==1 ? Wtp1 : Wtp2);
    const float* atp = layer==0 ? a_tp0 : (layer==1 ? a_tp1 : a_tp2);
    float* c = cvec + (layer==0 ? 0 : (layer==1 ? 16 : 32));
    int NH = (layer==2) ? 1 : 16;
    int t = threadIdx.x;
    buf[t] = Wtp[t] * atp[t];
    __syncthreads();
    int F = 256 / NH;
    if (t < NH){
      float s = 0.f;
      for (int f = 0; f < F; f++) s += buf[t*F + f];
      c[t] = s;
    }
  } else {
    int i = (b - 1027)*256 + threadIdx.x;
    if (i < N) counts[i] = 0;
  }
}

// ---------------- CSR build (sort edges by target) ----------------
// hist + per-edge rank (rank = position among same-tgt edges in list order)
__global__ void k_hist(const int* tgt, int* counts, int* rank, int E){
  int i = blockIdx.x*blockDim.x + threadIdx.x;
  if (i < E) rank[i] = atomicAdd(&counts[tgt[i]], 1);
}
__global__ void k_scan1(const int* counts, int* row_excl, int* partials, int N){
  __shared__ int buf[1024];
  int t = threadIdx.x; int i = blockIdx.x*1024 + t;
  int v = (i < N) ? counts[i] : 0;
  buf[t] = v; __syncthreads();
  for (int o = 1; o < 1024; o <<= 1){
    int x = (t >= o) ? buf[t-o] : 0;
    __syncthreads();
    buf[t] += x;
    __syncthreads();
  }
  if (i < N) row_excl[i] = buf[t] - v;
  if (t == 1023) partials[blockIdx.x] = buf[1023];
}
// adds global prefix of partials (computed in-block, NB<=64) and finalizes row_start
__global__ void k_scan3(int* row_start, const int* partials, int N, int E){
  __shared__ int base;
  int b = blockIdx.x;
  int pb = (b*256) >> 10;
  if (threadIdx.x == 0){
    int s = 0;
    for (int k = 0; k < pb; k++) s += partials[k];
    base = s;
  }
  __syncthreads();
  int i = b*256 + threadIdx.x;
  if (i < N) row_start[i] += base;
  if (i == 0) row_start[N] = E;
}
// atomic-free scatter: p = row_start[tgt] + rank; nontemporal 8B store (bypass L2 —
// partial-line writes go to fabric with byte enables instead of 8x line amplification)
__global__ void k_scatter(const int* src, const int* tgt, const float* eprob,
                          const int* row_start, const int* rank,
                          long long* es, int E){
  int i = blockIdx.x*blockDim.x + threadIdx.x;
  if (i >= E) return;
  int p = row_start[tgt[i]] + rank[i];
  unsigned long long v = ((unsigned long long)(unsigned)__float_as_int(eprob[i]) << 32)
                       | (unsigned)src[i];
  __builtin_nontemporal_store((long long)v, es + p);
}

// ---------------- LDS-staged MFMA GEMM (fp16/fp32 in, fp16/int8 out) ----------------
// AF32: A operand is fp32 (node features) — converted in-register on load.
// y=0: proj -> int8 C8+pscale (if non-null), optional fp16 C1b, fused NH=16 svec
//      (asrc/atgt) or fused NH=1 svec (asrc1/atgt1, full-row dot via LDS reduce).
// y=1: skip -> fp16 C2b.
template<int AF32>
__device__ __forceinline__ s16x8 loadA(const void* Ab, size_t off){
  if constexpr (AF32){
    const float* p = (const float*)Ab + off;
    float4 a0 = *(const float4*)p;
    float4 a1 = *(const float4*)(p + 4);
    s16x8 r;
    r[0]=f2h(a0.x); r[1]=f2h(a0.y); r[2]=f2h(a0.z); r[3]=f2h(a0.w);
    r[4]=f2h(a1.x); r[5]=f2h(a1.y); r[6]=f2h(a1.z); r[7]=f2h(a1.w);
    return r;
  } else {
    return *(const s16x8*)((const short*)Ab + off);
  }
}

template<int KC, int AF32>   // K/32 chunks: 4 (K=128) or 8 (K=256)
__global__ __launch_bounds__(256)
void k_gemm_lds(const void* __restrict__ Ab,
                const short* __restrict__ B1t, const short* __restrict__ B2t,
                short* __restrict__ C1b, short* __restrict__ C2b,
                unsigned char* __restrict__ C8, float* __restrict__ pscale,
                const float* __restrict__ asrc, const float* __restrict__ atgt,
                const float* __restrict__ asrc1, const float* __restrict__ atgt1,
                float* __restrict__ s_src, float* __restrict__ s_tgt, int M){
  const int K = KC*32;
  __shared__ short lA[64*32];     // 4 KB
  __shared__ short lB[256*32];    // 16 KB
  const int tid  = threadIdx.x;
  const int lane = tid & 63;
  const int wave = tid >> 6;
  const int m16  = lane & 15;
  const int q    = lane >> 4;
  const int swz  = (m16 >> 1) & 3;
  const int r0   = blockIdx.x * 64;
  const bool first = (blockIdx.y == 0);
  const short* __restrict__ Bt = first ? B1t : B2t;
  short* __restrict__ Cb = first ? C1b : C2b;

  int arow = r0 + (tid >> 2); if (arow >= M) arow = M - 1;
  const int akq = (tid & 3) ^ ((tid >> 3) & 3);
  int bn[4], bkq[4];
  #pragma unroll
  for (int j = 0; j < 4; j++){
    int sj = j*256 + tid;
    bn[j]  = sj >> 2;
    bkq[j] = (sj & 3) ^ ((sj >> 3) & 3);
  }

  f32x4 acc[4][4];
  #pragma unroll
  for (int mi = 0; mi < 4; mi++)
    #pragma unroll
    for (int ni = 0; ni < 4; ni++) acc[mi][ni] = {0.f,0.f,0.f,0.f};

  s16x8 ra = loadA<AF32>(Ab, (size_t)arow*K + akq*8);
  s16x8 rb[4];
  #pragma unroll
  for (int j = 0; j < 4; j++)
    rb[j] = *(const s16x8*)(Bt + (size_t)bn[j]*K + bkq[j]*8);

  for (int c = 0; c < KC; c++){
    __syncthreads();
    *(s16x8*)(lA + tid*8) = ra;
    #pragma unroll
    for (int j = 0; j < 4; j++)
      *(s16x8*)(lB + (j*256 + tid)*8) = rb[j];
    __syncthreads();

    if (c + 1 < KC){
      int k0 = (c+1)*32;
      ra = loadA<AF32>(Ab, (size_t)arow*K + k0 + akq*8);
      #pragma unroll
      for (int j = 0; j < 4; j++)
        rb[j] = *(const s16x8*)(Bt + (size_t)bn[j]*K + k0 + bkq[j]*8);
    }

    s16x8 Af[4], Bf[4];
    #pragma unroll
    for (int mi = 0; mi < 4; mi++){
      int slot = (mi*16 + m16)*4 + (q ^ swz);
      Af[mi] = *(const s16x8*)(lA + slot*8);
    }
    #pragma unroll
    for (int ni = 0; ni < 4; ni++){
      int n = wave*64 + ni*16 + m16;
      int slot = n*4 + (q ^ swz);
      Bf[ni] = *(const s16x8*)(lB + slot*8);
    }
    #pragma unroll
    for (int mi = 0; mi < 4; mi++)
      #pragma unroll
      for (int ni = 0; ni < 4; ni++)
        acc[mi][ni] = __builtin_amdgcn_mfma_f32_16x16x32_f16(
            *(h16x8*)&Bf[ni], *(h16x8*)&Af[mi], acc[mi][ni], 0, 0, 0);
  }

  #pragma unroll
  for (int mi = 0; mi < 4; mi++){
    int row = r0 + mi*16 + m16;
    bool ok = (row < M);
    #pragma unroll
    for (int ni = 0; ni < 4; ni++){
      if (ok && Cb){
        size_t o = (size_t)row*256 + wave*64 + ni*16 + q*4;
        short4 u; u.x = f2h(acc[mi][ni][0]); u.y = f2h(acc[mi][ni][1]);
        u.z = f2h(acc[mi][ni][2]); u.w = f2h(acc[mi][ni][3]);
        *(short4*)(Cb + o) = u;
      }
      if (first && asrc){
        // fused NH=16 svec: head hh = wave*4+ni; lane holds features q*4..q*4+3
        int hh = wave*4 + ni;
        const float* as = asrc + hh*16 + q*4;
        const float* at = atgt + hh*16 + q*4;
        float pss = acc[mi][ni][0]*as[0] + acc[mi][ni][1]*as[1]
                  + acc[mi][ni][2]*as[2] + acc[mi][ni][3]*as[3];
        float pst = acc[mi][ni][0]*at[0] + acc[mi][ni][1]*at[1]
                  + acc[mi][ni][2]*at[2] + acc[mi][ni][3]*at[3];
        pss += __shfl_xor(pss, 16); pss += __shfl_xor(pss, 32);
        pst += __shfl_xor(pst, 16); pst += __shfl_xor(pst, 32);
        if (ok && q == 0){
          s_src[row*16 + hh] = pss;
          s_tgt[row*16 + hh] = pst;
        }
      }
    }
  }

  // ---- fused NH=1 svec (layer 2): full 256-col dot per row, cross-wave LDS reduce ----
  if (first && asrc1){
    float pss[4], pst[4];
    #pragma unroll
    for (int mi = 0; mi < 4; mi++){
      float ss = 0.f, st = 0.f;
      #pragma unroll
      for (int ni = 0; ni < 4; ni++){
        const float* as = asrc1 + wave*64 + ni*16 + q*4;
        const float* at = atgt1 + wave*64 + ni*16 + q*4;
        #pragma unroll
        for (int k = 0; k < 4; k++){
          ss += acc[mi][ni][k]*as[k];
          st += acc[mi][ni][k]*at[k];
        }
      }
      ss += __shfl_xor(ss, 16); ss += __shfl_xor(ss, 32);
      st += __shfl_xor(st, 16); st += __shfl_xor(st, 32);
      pss[mi] = ss; pst[mi] = st;
    }
    __syncthreads();                       // main-loop lB reads done
    float* sred = (float*)lB;              // [2][4 waves][64 rows] = 2 KB
    if (q == 0){
      #pragma unroll
      for (int mi = 0; mi < 4; mi++){
        int r = mi*16 + m16;
        sred[wave*64 + r]       = pss[mi];
        sred[256 + wave*64 + r] = pst[mi];
      }
    }
    __syncthreads();
    if (tid < 64){
      int row = r0 + tid;
      if (row < M){
        float ss = sred[tid] + sred[64+tid] + sred[128+tid] + sred[192+tid];
        float st = sred[256+tid] + sred[320+tid] + sred[384+tid] + sred[448+tid];
        s_src[row] = ss;
        s_tgt[row] = st;
      }
    }
  }

  // ---- per-row-scaled int8 encode (message proj, all layers) ----
  if (first && C8){
    // row max |x| over 256 cols: reduce over k,ni (in-lane), q (shfl), waves (LDS)
    float am[4];
    #pragma unroll
    for (int mi = 0; mi < 4; mi++){
      float a = 0.f;
      #pragma unroll
      for (int ni = 0; ni < 4; ni++)
        #pragma unroll
        for (int k = 0; k < 4; k++)
          a = fmaxf(a, fabsf(acc[mi][ni][k]));
      a = fmaxf(a, __shfl_xor(a, 16));
      a = fmaxf(a, __shfl_xor(a, 32));
      am[mi] = a;
    }
    __syncthreads();                      // all waves done with prior LDS use
    float* rmax = (float*)lA;             // [wave][64 rows] = 1 KB, reuse lA
    if (q == 0){
      #pragma unroll
      for (int mi = 0; mi < 4; mi++) rmax[wave*64 + mi*16 + m16] = am[mi];
    }
    __syncthreads();
    #pragma unroll
    for (int mi = 0; mi < 4; mi++){
      int r = mi*16 + m16;
      int row = r0 + r;
      bool ok = (row < M);
      float s = fmaxf(fmaxf(rmax[r], rmax[64+r]), fmaxf(rmax[128+r], rmax[192+r]));
      float scl = s * (1.f/127.f);
      float inv = (s > 0.f) ? (127.f/s) : 0.f;
      if (ok && wave == 0 && q == 0) pscale[row] = scl;
      if (ok){
        #pragma unroll
        for (int ni = 0; ni < 4; ni++){
          int v0 = __float2int_rn(acc[mi][ni][0]*inv) + 128;
          int v1 = __float2int_rn(acc[mi][ni][1]*inv) + 128;
          int v2 = __float2int_rn(acc[mi][ni][2]*inv) + 128;
          int v3 = __float2int_rn(acc[mi][ni][3]*inv) + 128;
          unsigned pk = (unsigned)(v0 & 255) | ((unsigned)(v1 & 255) << 8)
                      | ((unsigned)(v2 & 255) << 16) | ((unsigned)(v3 & 255) << 24);
          *(unsigned*)(C8 + (size_t)row*256 + wave*64 + ni*16 + q*4) = pk;
        }
      }
    }
  }
}

// ---------------- single-pass fused attention, NH=16 (int8 proj gather) ----------------
template<int LN>
__global__ __launch_bounds__(256)
void k_attn16(const int* __restrict__ row_start, const int2* __restrict__ es,
              const float* __restrict__ s_src, const float* __restrict__ s_tgt,
              const float* __restrict__ cvec,
              const unsigned char* __restrict__ proj8, const float* __restrict__ pscale,
              const short* __restrict__ skipb,
              const float* __restrict__ bias,
              const float* __restrict__ ln_g, const float* __restrict__ ln_b,
              short* __restrict__ houtb, int N){
  __shared__ __align__(16) float wbuf[4][16][20];   // [wave][head][edge(16)+pad]
  __shared__ __align__(16) int   svbuf[4][16];
  __shared__ __align__(16) float scbuf[4][16];
  const int lane = threadIdx.x & 63;
  const int wave = threadIdx.x >> 6;
  const int node = blockIdx.x*4 + wave;
  if (node >= N) return;
  const int beg = row_start[node], end = row_start[node+1];

  const int h2 = lane >> 2;      // head owning this lane's 4 features (aggregation)
  const int j4 = lane & 15;      // edge slot (score phase)
  const int g  = lane >> 4;      // head-quad (score phase)

  const f32x4 stg = *(const f32x4*)(s_tgt + (size_t)node*16 + g*4);
  const f32x4 cg  = *(const f32x4*)(cvec + g*4);

  float d = 0.f, dws = 0.f;
  float acc0 = 0.f, acc1 = 0.f, acc2 = 0.f, acc3 = 0.f;

  for (int s0 = beg; s0 < end; s0 += 16){
    int cnt = end - s0; if (cnt > 16) cnt = 16;
    // ---- Phase A: scores for 16 edges x 16 heads ----
    int i  = s0 + j4;
    bool valid = (i < end);
    int ic = valid ? i : (end - 1);
    int2 e2 = es[ic];
    int sv = e2.x;
    float tp = __int_as_float(e2.y);
    f32x4 rv = *(const f32x4*)(s_src + (size_t)sv*16 + g*4);
    if (g == 0){ svbuf[wave][j4] = sv; scbuf[wave][j4] = pscale[sv]; }
    #pragma unroll
    for (int k = 0; k < 4; k++){
      float e = rv[k] + stg[k] + tp*cg[k];
      e = (e > 0.f) ? e : 0.2f*e;
      wbuf[wave][g*4 + k][j4] = valid ? __expf(e) : 0.f;
    }
    // ---- Phase B: int8 gather + f32 accumulate (pads carry w=0, sv clamped) ----
    const unsigned* __restrict__ pp = (const unsigned*)proj8 + lane;
    for (int j = 0; j < cnt; j += 4){
      f32x4 w4  = *(const f32x4*)&wbuf[wave][h2][j];
      f32x4 sc4 = *(const f32x4*)&scbuf[wave][j];
      i32x4 sv4 = *(const i32x4*)&svbuf[wave][j];
      unsigned q0 = pp[(size_t)sv4.x*64];
      unsigned q1 = pp[(size_t)sv4.y*64];
      unsigned q2 = pp[(size_t)sv4.z*64];
      unsigned q3 = pp[(size_t)sv4.w*64];
      float ws0 = w4.x*sc4.x, ws1 = w4.y*sc4.y, ws2 = w4.z*sc4.z, ws3 = w4.w*sc4.w;
      d   += (w4.x + w4.y) + (w4.z + w4.w);
      dws += (ws0 + ws1) + (ws2 + ws3);
      acc0 += ws0*(float)(q0 & 255) + ws1*(float)(q1 & 255)
            + ws2*(float)(q2 & 255) + ws3*(float)(q3 & 255);
      acc1 += ws0*(float)((q0 >> 8) & 255) + ws1*(float)((q1 >> 8) & 255)
            + ws2*(float)((q2 >> 8) & 255) + ws3*(float)((q3 >> 8) & 255);
      acc2 += ws0*(float)((q0 >> 16) & 255) + ws1*(float)((q1 >> 16) & 255)
            + ws2*(float)((q2 >> 16) & 255) + ws3*(float)((q3 >> 16) & 255);
      acc3 += ws0*(float)(q0 >> 24) + ws1*(float)(q1 >> 24)
            + ws2*(float)(q2 >> 24) + ws3*(float)(q3 >> 24);
    }
  }
  float inv = 1.f / (d + 1e-16f);
  float c128 = 128.f * dws;

  short4 sk = ((const short4*)(skipb + (size_t)node*256))[lane];
  float acc[4];
  acc[0] = (acc0 - c128)*inv + h2f(sk.x); acc[1] = (acc1 - c128)*inv + h2f(sk.y);
  acc[2] = (acc2 - c128)*inv + h2f(sk.z); acc[3] = (acc3 - c128)*inv + h2f(sk.w);

  #pragma unroll
  for (int j = 0; j < 4; j++){
    float v = acc[j] + bias[lane*4 + j];
    acc[j] = (v > 0.f) ? v : (__expf(v) - 1.f);
  }
  if (LN){
    float s  = acc[0] + acc[1] + acc[2] + acc[3];
    float s2 = acc[0]*acc[0] + acc[1]*acc[1] + acc[2]*acc[2] + acc[3]*acc[3];
    for (int o = 32; o > 0; o >>= 1){ s += __shfl_xor(s, o); s2 += __shfl_xor(s2, o); }
    float mu  = s * (1.f/256.f);
    float var = s2 * (1.f/256.f) - mu*mu;
    float rs  = rsqrtf(var + 1e-5f);
    #pragma unroll
    for (int j = 0; j < 4; j++)
      acc[j] = (acc[j] - mu)*rs*ln_g[lane*4 + j] + ln_b[lane*4 + j];
  }
  short4 ub; ub.x = f2h(acc[0]); ub.y = f2h(acc[1]);
  ub.z = f2h(acc[2]); ub.w = f2h(acc[3]);
  ((short4*)(houtb + (size_t)node*256))[lane] = ub;
}

// NH=1 variant (layer 2): int8 message gather; scores from fused GEMM-epilogue svec.
// Identity skip, LN, fp16 out.
__global__ __launch_bounds__(256)
void k_attn1(const int* __restrict__ row_start, const int2* __restrict__ es,
             const float* __restrict__ s_src, const float* __restrict__ s_tgt,
             const float* __restrict__ cvec,
             const unsigned char* __restrict__ proj8, const float* __restrict__ pscale,
             const short* __restrict__ skipb,
             const float* __restrict__ bias,
             const float* __restrict__ ln_g, const float* __restrict__ ln_b,
             short* __restrict__ houtb, int N){
  __shared__ __align__(16) float wb1[4][64];
  __shared__ __align__(16) int   sb1[4][64];
  __shared__ __align__(16) float scb1[4][64];
  const int lane = threadIdx.x & 63;
  const int wave = threadIdx.x >> 6;
  const int node = blockIdx.x*4 + wave;
  if (node >= N) return;
  const int beg = row_start[node], end = row_start[node+1];

  const float c0 = cvec[0];
  const float st = s_tgt[node];
  float d = 0.f, dws = 0.f;
  float acc0 = 0.f, acc1 = 0.f, acc2 = 0.f, acc3 = 0.f;

  for (int s0 = beg; s0 < end; s0 += 64){
    int cnt = end - s0; if (cnt > 64) cnt = 64;
    // ---- Phase A: one edge per lane ----
    int i  = s0 + lane;
    bool valid = (i < end);
    int ic = valid ? i : (end - 1);
    int2 e2 = es[ic];
    int sv = e2.x;
    float e = s_src[sv] + st + __int_as_float(e2.y)*c0;
    e = (e > 0.f) ? e : 0.2f*e;
    float w = valid ? __expf(e) : 0.f;
    wb1[wave][lane] = w;
    sb1[wave][lane] = sv;
    scb1[wave][lane] = pscale[sv];
    // ---- Phase B: int8 gather + f32 accumulate (pads carry w=0, sv clamped) ----
    const unsigned* __restrict__ pp = (const unsigned*)proj8 + lane;
    for (int j = 0; j < cnt; j += 4){
      f32x4 w4  = *(const f32x4*)&wb1[wave][j];
      f32x4 sc4 = *(const f32x4*)&scb1[wave][j];
      i32x4 sv4 = *(const i32x4*)&sb1[wave][j];
      unsigned q0 = pp[(size_t)sv4.x*64];
      unsigned q1 = pp[(size_t)sv4.y*64];
      unsigned q2 = pp[(size_t)sv4.z*64];
      unsigned q3 = pp[(size_t)sv4.w*64];
      float ws0 = w4.x*sc4.x, ws1 = w4.y*sc4.y, ws2 = w4.z*sc4.z, ws3 = w4.w*sc4.w;
      d   += (w4.x + w4.y) + (w4.z + w4.w);
      dws += (ws0 + ws1) + (ws2 + ws3);
      acc0 += ws0*(float)(q0 & 255) + ws1*(float)(q1 & 255)
            + ws2*(float)(q2 & 255) + ws3*(float)(q3 & 255);
      acc1 += ws0*(float)((q0 >> 8) & 255) + ws1*(float)((q1 >> 8) & 255)
            + ws2*(float)((q2 >> 8) & 255) + ws3*(float)((q3 >> 8) & 255);
      acc2 += ws0*(float)((q0 >> 16) & 255) + ws1*(float)((q1 >> 16) & 255)
            + ws2*(float)((q2 >> 16) & 255) + ws3*(float)((q3 >> 16) & 255);
      acc3 += ws0*(float)(q0 >> 24) + ws1*(float)(q1 >> 24)
            + ws2*(float)(q2 >> 24) + ws3*(float)(q3 >> 24);
    }
  }
  float inv = 1.f / (d + 1e-16f);
  float c128 = 128.f * dws;

  short4 sk = ((const short4*)(skipb + (size_t)node*256))[lane];
  float acc[4];
  acc[0] = (acc0 - c128)*inv + h2f(sk.x); acc[1] = (acc1 - c128)*inv + h2f(sk.y);
  acc[2] = (acc2 - c128)*inv + h2f(sk.z); acc[3] = (acc3 - c128)*inv + h2f(sk.w);

  #pragma unroll
  for (int j = 0; j < 4; j++){
    float v = acc[j] + bias[lane*4 + j];
    acc[j] = (v > 0.f) ? v : (__expf(v) - 1.f);
  }
  float s  = acc[0] + acc[1] + acc[2] + acc[3];
  float s2 = acc[0]*acc[0] + acc[1]*acc[1] + acc[2]*acc[2] + acc[3]*acc[3];
  for (int o = 32; o > 0; o >>= 1){ s += __shfl_xor(s, o); s2 += __shfl_xor(s2, o); }
  float mu  = s * (1.f/256.f);
  float var = s2 * (1.f/256.f) - mu*mu;
  float rs  = rsqrtf(var + 1e-5f);
  #pragma unroll
  for (int j = 0; j < 4; j++)
    acc[j] = (acc[j] - mu)*rs*ln_g[lane*4 + j] + ln_b[lane*4 + j];
  short4 ub; ub.x = f2h(acc[0]); ub.y = f2h(acc[1]);
  ub.z = f2h(acc[2]); ub.w = f2h(acc[3]);
  ((short4*)(houtb + (size_t)node*256))[lane] = ub;
}

// ---------------- final gather (fp16 h -> fp32 out) ----------------
__global__ void k_gather(const short* hb, const int* x, float* out, int R){
  int r = blockIdx.x, t = threadIdx.x;
  if (r >= R) return;
  out[(size_t)r*256 + t] = h2f(hb[(size_t)x[r]*256 + t]);
}

extern "C" void kernel_launch(void* const* d_in, const int* in_sizes, int n_in,
                              void* d_out, int out_size, void* d_ws, size_t ws_size,
                              hipStream_t stream){
  const int N = in_sizes[0] / 128;   // 50000
  const int E = in_sizes[1] / 2;     // 800000
  const int R = in_sizes[3];         // 8192

  const float* nf    = (const float*)d_in[0];
  const int*   ei    = (const int*)d_in[1];
  const float* eprob = (const float*)d_in[2];
  const int*   xidx  = (const int*)d_in[3];
  const float* W0     = (const float*)d_in[4];
  const float* a_src0 = (const float*)d_in[5];
  const float* a_tgt0 = (const float*)d_in[6];
  const float* Wtp0   = (const float*)d_in[7];
  const float* a_tp0  = (const float*)d_in[8];
  const float* Wskip0 = (const float*)d_in[9];
  const float* b0     = (const float*)d_in[10];
  const float* W1     = (const float*)d_in[11];
  const float* a_src1 = (const float*)d_in[12];
  const float* a_tgt1 = (const float*)d_in[13];
  const float* Wtp1   = (const float*)d_in[14];
  const float* a_tp1  = (const float*)d_in[15];
  const float* Wskip1 = (const float*)d_in[16];
  const float* b1     = (const float*)d_in[17];
  const float* ln1_g  = (const float*)d_in[18];
  const float* ln1_b  = (const float*)d_in[19];
  const float* W2     = (const float*)d_in[20];
  const float* a_src2 = (const float*)d_in[21];
  const float* a_tgt2 = (const float*)d_in[22];
  const float* Wtp2   = (const float*)d_in[23];
  const float* a_tp2  = (const float*)d_in[24];
  const float* b2     = (const float*)d_in[25];
  const float* ln2_g  = (const float*)d_in[26];
  const float* ln2_b  = (const float*)d_in[27];

  // ---- workspace layout (~80 MB) ----
  char* ws = (char*)d_ws;
  size_t off = 0;
  auto alloc = [&](size_t bytes)->char*{
    char* p = ws + off; off = (off + bytes + 255) & ~(size_t)255; return p;
  };
  unsigned char* P8 = (unsigned char*)alloc((size_t)N*256);  // proj, int8 (all layers)
  float* pscale    = (float*)alloc((size_t)N*4);       // per-row int8 scale
  short* hXb       = (short*)alloc((size_t)N*256*2);   // fp16 h: L0 out, then L1 out
  short* Skb       = (short*)alloc((size_t)N*256*2);   // skip GEMM out (L0/L1), then final h
  float* s_src     = (float*)alloc((size_t)N*16*4);
  float* s_tgt     = (float*)alloc((size_t)N*16*4);
  float* cvec      = (float*)alloc(256);
  int*   counts    = (int*)alloc((size_t)N*4);
  int*   row_start = (int*)alloc((size_t)(N+1)*4);
  int*   partials  = (int*)alloc(256*4);
  int*   rank      = (int*)alloc((size_t)E*4);         // per-edge rank within tgt
  int2*  es        = (int2*)alloc((size_t)E*8);        // packed (src, tp) sorted by tgt
  short* W0t       = (short*)alloc((size_t)128*256*2);
  short* Ws0t      = (short*)alloc((size_t)128*256*2);
  short* W1t       = (short*)alloc((size_t)256*256*2);
  short* Ws1t      = (short*)alloc((size_t)256*256*2);
  short* W2t       = (short*)alloc((size_t)256*256*2);
  (void)ws_size; (void)n_in; (void)out_size;

  const int* src = ei;
  const int* tgt = ei + E;

  // ---- prep: fused transposes+cvecs+counts-zero ----
  int prep_blocks = 1027 + (N + 255)/256;
  k_prep<<<prep_blocks, 256, 0, stream>>>(W0, Wskip0, W1, Wskip1, W2,
                                          W0t, Ws0t, W1t, Ws1t, W2t,
                                          Wtp0, a_tp0, Wtp1, a_tp1, Wtp2, a_tp2, cvec,
                                          counts, N);

  // ---- CSR build (atomic-free scatter via precomputed ranks) ----
  k_hist<<<(E+255)/256, 256, 0, stream>>>(tgt, counts, rank, E);
  int NB = (N + 1023) / 1024;
  k_scan1<<<NB, 1024, 0, stream>>>(counts, row_start, partials, N);
  k_scan3<<<(N+255)/256, 256, 0, stream>>>(row_start, partials, N, E);
  k_scatter<<<(E+255)/256, 256, 0, stream>>>(src, tgt, eprob, row_start, rank,
                                             (long long*)es, E);

  const int gt = (N + 63) / 64;   // GEMM m-tiles
  const int at = (N + 3) / 4;     // attn blocks (4 waves each)

  // ---- Layer 0: GAT(128 -> 16x16 concat), skip = nf @ Wskip0, ELU, no LN ----
  // A operand is raw fp32 node features (converted in-register; k_cvt deleted).
  k_gemm_lds<4,1><<<dim3(gt,2), 256, 0, stream>>>(nf, W0t, Ws0t, nullptr, Skb, P8, pscale,
                                                  a_src0, a_tgt0, nullptr, nullptr,
                                                  s_src, s_tgt, N);
  k_attn16<0><<<at, 256, 0, stream>>>(row_start, es, s_src, s_tgt, cvec + 0,
                                      P8, pscale, Skb, b0, nullptr, nullptr, hXb, N);

  // ---- Layer 1: GAT(256 -> 16x16 concat), skip = h @ Wskip1, ELU, LN ----
  k_gemm_lds<8,0><<<dim3(gt,2), 256, 0, stream>>>(hXb, W1t, Ws1t, nullptr, Skb, P8, pscale,
                                                  a_src1, a_tgt1, nullptr, nullptr,
                                                  s_src, s_tgt, N);
  k_attn16<1><<<at, 256, 0, stream>>>(row_start, es, s_src, s_tgt, cvec + 16,
                                      P8, pscale, Skb, b1, ln1_g, ln1_b, hXb, N);

  // ---- Layer 2: GAT(256 -> 1x256, avg = identity), identity skip, ELU, LN ----
  // GEMM emits int8 P8 + pscale and fused NH=1 svec (s_src/s_tgt from exact f32).
  k_gemm_lds<8,0><<<dim3(gt,1), 256, 0, stream>>>(hXb, W2t, nullptr, nullptr, nullptr,
                                                  P8, pscale,
                                                  nullptr, nullptr, a_src2, a_tgt2,
                                                  s_src, s_tgt, N);
  k_attn1<<<at, 256, 0, stream>>>(row_start, es, s_src, s_tgt, cvec + 32,
                                  P8, pscale, hXb, b2, ln2_g, ln2_b, Skb, N);

  // ---- gather rows into output (fp32) ----
  k_gather<<<R, 256, 0, stream>>>(Skb, xidx, (float*)d_out, R);
}